// Round 5
// baseline (1218.247 us; speedup 1.0000x reference)
//
#include <hip/hip_runtime.h>
#include <math.h>

// SwarmSetEquivariantTorso — bf16 MFMA, fully wave-private, ZERO barriers.
// Block = 256 threads = 4 independent waves; each wave owns 3 tokens
// (15 slot rows = one 16-row MFMA M-tile). Every GEMM is per-wave:
// A-fragment hoisted once per layer (2-5 ds_read_b128), B (weights) streamed
// from a pre-transposed bf16 image in d_ws (W_t[n][k]). No __syncthreads
// anywhere — in-wave lgkmcnt ordering suffices. Pad rows (>= real count)
// carry garbage; MFMA confines row m of D to row m of A, stores are guarded.

#define DOBS 198
#define NEG_INF_F (-3.402823466e38f)

typedef __bf16 v8bf __attribute__((ext_vector_type(8)));
typedef float  v4f  __attribute__((ext_vector_type(4)));

struct P {
  const float *obs,*tok_w,*tok_b,*ln1_s,*ln1_b,
    *a1_qw,*a1_qb,*a1_kw,*a1_kb,*a1_vw,*a1_vb,*a1_ow,*a1_ob,
    *ln2_s,*ln2_b,*m1_w,*m1_b,*m2_w,*m2_b,*m3_w,*m3_b,
    *e1_w,*e1_b,*e2_w,*e2_b,*e3_w,*e3_b,
    *l1_w,*l1_b,*l2_w,*l2_b,*l3_w,*l3_b,
    *seed,*p_qw,*p_qb,*p_kw,*p_kb,*p_vw,*p_vb,*p_ow,*p_ob,
    *pr_w,*pr_b,*h1_w,*h1_b,*h2_w,*h2_b,*h3_w,*h3_b;
  float* out;
};
static_assert(sizeof(P) == 51*sizeof(void*), "P layout");

// ws bf16 weight image, W_t[n][k] per matrix (element offsets)
#define W_A1Q 0
#define W_A1K 4096
#define W_A1V 8192
#define W_A1O 12288
#define W_M1  16384
#define W_M2  24576
#define W_M3  40960
#define W_E1  49152
#define W_E2  53248
#define W_E3  69632
#define W_L1  77824
#define W_L2  94208
#define W_PK  110592
#define W_PV  114688
#define W_PO  118784
#define W_H1  122880
#define W_H2  143360
#define W_H3  159744
#define W_END 176128

__global__ __launch_bounds__(256)
void prep_w(P a, __bf16* ws)
{
  const float* srcs[18] = {a.a1_qw,a.a1_kw,a.a1_vw,a.a1_ow,a.m1_w,a.m2_w,a.m3_w,
                           a.e1_w,a.e2_w,a.e3_w,a.l1_w,a.l2_w,a.p_kw,a.p_vw,a.p_ow,
                           a.h1_w,a.h2_w,a.h3_w};
  const int Ks[18]   = {64,64,64,64,64,128,128,32,128,128,128,128,64,64,64,160,128,128};
  const int Ns[18]   = {64,64,64,64,128,128,64,128,128,64,128,128,64,64,64,128,128,128};
  const int offs[18] = {W_A1Q,W_A1K,W_A1V,W_A1O,W_M1,W_M2,W_M3,W_E1,W_E2,W_E3,
                        W_L1,W_L2,W_PK,W_PV,W_PO,W_H1,W_H2,W_H3};
  __shared__ float tile[32][33];
  int b = blockIdx.x, m = 0, acc = 0;
  for (; m < 18; m++){
    int t = (Ks[m]/32)*(Ns[m]/32);
    if (b < acc + t) break;
    acc += t;
  }
  int lt = b - acc, K = Ks[m], N = Ns[m];
  int ntile = N/32, kt = lt/ntile, nt = lt%ntile;
  int tx = threadIdx.x & 31, ty = threadIdx.x >> 5;
  const float* S = srcs[m];
  #pragma unroll
  for (int rr=0; rr<32; rr+=8)
    tile[ty+rr][tx] = S[(size_t)(kt*32+ty+rr)*N + nt*32+tx];
  __syncthreads();
  __bf16* D = ws + offs[m];
  #pragma unroll
  for (int rr=0; rr<32; rr+=8)
    D[(size_t)(nt*32+ty+rr)*K + kt*32+tx] = (__bf16)tile[tx][ty+rr];
}

__device__ __forceinline__ float gelu_f(float x){
  float t = 0.7978845608028654f * (x + 0.044715f*x*x*x);
  float e = __expf(2.0f*t);
  float th = 1.0f - 2.0f/(e+1.0f);
  return 0.5f * x * (1.0f + th);
}

__device__ __forceinline__ float wsum(float v){
  #pragma unroll
  for (int off=32; off>0; off>>=1) v += __shfl_xor(v, off, 64);
  return v;
}

__device__ __forceinline__ void load16f(const __bf16* p, float* f){
  v8bf a = *(const v8bf*)p, b = *(const v8bf*)(p+8);
  #pragma unroll
  for (int i=0;i<8;i++){ f[i]=(float)a[i]; f[8+i]=(float)b[i]; }
}

template<int KT> struct Frag { v8bf v[KT]; };

template<int KT>
__device__ __forceinline__ Frag<KT> loadA(const __bf16* A, int lda, int lane){
  Frag<KT> f;
  const __bf16* p = A + (size_t)(lane&15)*lda + (lane>>4)*8;
  #pragma unroll
  for (int kt=0;kt<KT;kt++) f.v[kt] = *(const v8bf*)(p + kt*32);
  return f;
}

// wave-private GEMM: D[16 x ntiles*16] = A @ W + bias; A-fragment preloaded.
template<int KT, typename E>
__device__ __forceinline__ void gemmF(const Frag<KT>& fa,
    const __bf16* __restrict__ Wt, int ntiles,
    const float* __restrict__ bias, int lane, E epi)
{
  const int col = lane&15, quad = lane>>4;
  const int K = KT*32;
  for (int nt=0;nt<ntiles;nt++){
    v4f c; float b0 = bias[nt*16+col];
    c[0]=b0;c[1]=b0;c[2]=b0;c[3]=b0;
    const __bf16* bp = Wt + (size_t)(nt*16+col)*K + quad*8;
    #pragma unroll
    for (int kt=0;kt<KT;kt++){
      v8bf bv = *(const v8bf*)(bp + kt*32);
      c = __builtin_amdgcn_mfma_f32_16x16x32_bf16(fa.v[kt], bv, c, 0, 0, 0);
    }
    epi(quad*4, nt*16+col, c);
  }
}

// Per-wave LDS (byte offsets within wave region, stride 13296, 16B aligned):
//  Ab  bf16[16][136] @0      4352  (early: Df f32[3][32] dist scratch)
//  Bb  bf16[16][136] @4352   4352
//  TkO               @8704   2304  (OBSf f32[3][120] -> Tk bf16[16][72] -> Po bf16[3][64])
//  Scr               @11008   768  (TOKIN f32[15][12] -> ATTb bf16[300] -> ECX bf16[3][64]
//                                   -> {Cc bf16[3][64] @0, pattn f32[60] @384})
//  Pe  bf16[3][64]   @11776   384
//  Eg  bf16[3][40]   @12160   240  (A-tile reads overspill; confined to pad rows)
//  Ru  f32[3][32]    @12400   384
//  Ax  f32[128]      @12784   512  (mf15|msf15|many3|lg15|alpha15|pad|qp64)
// Block total: 4*13296 + 768 tail pad (for Pe-fragment overspill) = 53952 B -> 3 blocks/CU.
#define WVSZ 13296

__global__ __launch_bounds__(256,3)
void swarm_mfma(P a, const __bf16* __restrict__ ws, int ntok)
{
  __shared__ char smem[4*WVSZ + 768] __attribute__((aligned(16)));
  const int tid  = threadIdx.x;
  const int lane = tid & 63;
  const int wv   = tid >> 6;
  char* wb = smem + wv*WVSZ;
  __bf16* Ab   = (__bf16*)(wb);
  __bf16* Bb   = (__bf16*)(wb+4352);
  float*  OBSf = (float*) (wb+8704);
  __bf16* Tk   = (__bf16*)(wb+8704);
  __bf16* Po   = (__bf16*)(wb+8704);
  float*  TOKIN= (float*) (wb+11008);
  __bf16* ATTb = (__bf16*)(wb+11008);
  __bf16* ECX  = (__bf16*)(wb+11008);
  __bf16* Cc   = (__bf16*)(wb+11008);
  float*  pattn= (float*) (wb+11008+384);
  __bf16* Pe   = (__bf16*)(wb+11776);
  __bf16* Eg   = (__bf16*)(wb+12160);
  float*  Ru   = (float*) (wb+12400);
  float*  Ax   = (float*) (wb+12784);
  float* mf    = Ax;      // [15]
  float* msf   = Ax+15;   // [15]
  float* many  = Ax+30;   // [3]
  float* lg    = Ax+33;   // [15]
  float* alpha = Ax+48;   // [15]
  float* qp    = Ax+64;   // [64]

  const long t0 = (long)blockIdx.x*12 + wv*3;   // this wave's first token

  // ---- P0: obs load (3 tokens x 117) + pooling query (redundant per wave) ----
  for (int it=lane; it<3*117; it+=64){
    int tg=it/117, c=it-tg*117;
    long gt=t0+tg; if (gt>ntok-1) gt=ntok-1;
    OBSf[tg*120+c] = a.obs[gt*DOBS+c];
  }
  { float acc=a.p_qb[lane];
    for (int k=0;k<64;k++) acc += a.seed[k]*a.p_qw[k*64+lane];
    qp[lane]=acc; }

  // ---- P1: masks + pair distances (Df scratch overlays Ab) ----
  float* Df = (float*)Ab;
  for (int it=lane; it<75; it+=64){
    int tg=it/25, p=it-tg*25, i=p/5, j=p-i*5;
    const float* ob = OBSf + tg*120 + 32;
    float d2=0.f;
    #pragma unroll
    for (int d=0;d<3;d++){
      float ri=ob[15*i+d]; ri = isfinite(ri)?ri:0.f;
      float rj=ob[15*j+d]; rj = isfinite(rj)?rj:0.f;
      float df=ri-rj; d2 += df*df;
    }
    Df[tg*32+p]=sqrtf(d2);
  }
  if (lane<15){
    int tg=lane/5, s=lane-tg*5;
    const float* b = OBSf + tg*120 + 32 + 15*s;
    mf[lane] = (fabsf(b[0])>1e-6f||fabsf(b[1])>1e-6f||fabsf(b[2])>1e-6f)?1.f:0.f;
  }
  if (lane<3){
    float any = mf[lane*5]+mf[lane*5+1]+mf[lane*5+2]+mf[lane*5+3]+mf[lane*5+4];
    float anyf = (any>0.f)?1.f:0.f; many[lane]=anyf;
    #pragma unroll
    for (int i=0;i<5;i++) msf[lane*5+i] = (anyf>0.f)? mf[lane*5+i] : (i==0?1.f:0.f);
  }
  if (lane<15){
    int tg=lane/5, i=lane-tg*5;
    float dmin=1e9f,dsum=0.f,cnt=0.f;
    #pragma unroll
    for (int j=0;j<5;j++){
      if (j!=i && mf[tg*5+i]>0.5f && mf[tg*5+j]>0.5f){
        float dd=Df[tg*32+i*5+j];
        dmin=fminf(dmin,dd); dsum+=dd; cnt+=1.f;
      }
    }
    TOKIN[lane*12+10]=dmin;
    TOKIN[lane*12+11]=(cnt>0.f)? dsum/(cnt+1e-9f) : 0.f;
  }

  // ---- P2: tok_in main, ego, ru, pair_emb (all from OBSf, before Tk overlay) ----
  for (int it=lane; it<150; it+=64){
    int tg=it/50, q=it-tg*50, s=q/10, c=q-s*10;
    const float* b = OBSf + tg*120 + 32 + 15*s;
    float v;
    if (c<4)        v=b[11+c];
    else if (c==4)  v=b[9];
    else if (c==5)  v=b[10];
    else if (c<9)   v=b[6+(c-6)];
    else { float a0=b[6],a1=b[7],a2=b[8]; v=sqrtf(a0*a0+a1*a1+a2*a2); }
    TOKIN[(tg*5+s)*12+c]=v;
  }
  for (int it=lane; it<96; it+=64){
    int tg=it>>5, c=it&31;
    Eg[tg*40+c] = (__bf16)OBSf[tg*120+c];
  }
  for (int it=lane; it<90; it+=64){
    int tg=it/30, c=it-tg*30;
    Ru[tg*32+c] = OBSf[tg*120+32+15*(c/6)+(c%6)];
  }
  for (int it=lane; it<192; it+=64){
    int tg=it>>6, c=it&63;
    float acc = a.pr_b[c];
    #pragma unroll
    for (int k=0;k<10;k++) acc += OBSf[tg*120+107+k]*a.pr_w[k*64+c];
    Pe[tg*64+c] = (__bf16)gelu_f(acc);
  }

  // ---- P3: tok embed (fp32 K=12) + mask + ln1; Tk overlays now-dead OBSf ----
  for (int r=0;r<15;r++){
    float acc = a.tok_b[lane];
    #pragma unroll
    for (int k=0;k<12;k++) acc += TOKIN[r*12+k]*a.tok_w[k*64+lane];
    float t = gelu_f(acc)*mf[r];
    Tk[r*72+lane] = (__bf16)t;
    float m = wsum(t)*(1.f/64.f);
    float d = t-m;
    float v = wsum(d*d)*(1.f/64.f);
    Ab[r*136+lane] = (__bf16)(d*(1.0f/sqrtf(v+1e-6f))*a.ln1_s[lane]+a.ln1_b[lane]);
  }

  // ---- QKV (shared A-fragment): K->Bb[64:], V->Ab[64:], Q->Bb[0:] ----
  {
    Frag<2> fa = loadA<2>(Ab,136,lane);
    gemmF<2>(fa, ws+W_A1K, 4, a.a1_kb, lane, [&](int r0,int cn,v4f c){
      #pragma unroll
      for (int r=0;r<4;r++) Bb[(r0+r)*136+64+cn]=(__bf16)c[r]; });
    gemmF<2>(fa, ws+W_A1V, 4, a.a1_vb, lane, [&](int r0,int cn,v4f c){
      #pragma unroll
      for (int r=0;r<4;r++) Ab[(r0+r)*136+64+cn]=(__bf16)c[r]; });
    gemmF<2>(fa, ws+W_A1Q, 4, a.a1_qb, lane, [&](int r0,int cn,v4f c){
      #pragma unroll
      for (int r=0;r<4;r++) Bb[(r0+r)*136+cn]=(__bf16)c[r]; });
  }

  // ---- attn weights (3 tok x 4 h x 5 i = 60 lanes) ----
  if (lane<60){
    int tg=lane/20, rem=lane-tg*20, h=rem/5, i=rem-h*5;
    bool mi = msf[tg*5+i]>0.5f;
    float q[16]; load16f(&Bb[(tg*5+i)*136 + h*16], q);
    float lgv[5], mx=NEG_INF_F;
    #pragma unroll
    for (int j=0;j<5;j++){
      float kk[16]; load16f(&Bb[(tg*5+j)*136 + 64 + h*16], kk);
      float d=0.f;
      #pragma unroll
      for (int dd=0;dd<16;dd++) d += q[dd]*kk[dd];
      bool mj = msf[tg*5+j]>0.5f;
      lgv[j] = (mi&&mj)? d*0.25f : NEG_INF_F;
      mx = fmaxf(mx,lgv[j]);
    }
    float sum=0.f, ex[5];
    #pragma unroll
    for (int j=0;j<5;j++){ ex[j]=__expf(lgv[j]-mx); sum+=ex[j]; }
    float inv=1.0f/sum;
    #pragma unroll
    for (int j=0;j<5;j++) ATTb[tg*100+(h*5+i)*5+j]=(__bf16)(ex[j]*inv);
  }

  // ---- o = attn @ V -> Ab[:,0:64] ----
  for (int r=0;r<15;r++){
    int tg=r/5, i=r-tg*5, h=lane>>4;
    float o=0.f;
    #pragma unroll
    for (int j=0;j<5;j++)
      o += (float)ATTb[tg*100+(h*5+i)*5+j]*(float)Ab[(tg*5+j)*136+64+lane];
    Ab[r*136+lane]=(__bf16)o;
  }

  // ---- o-proj + residual -> Tk ----
  {
    Frag<2> fa = loadA<2>(Ab,136,lane);
    gemmF<2>(fa, ws+W_A1O, 4, a.a1_ob, lane, [&](int r0,int cn,v4f c){
      #pragma unroll
      for (int r=0;r<4;r++){
        int R=r0+r; float mm=(R<15)?mf[R]:0.f;
        Tk[R*72+cn] = (__bf16)((float)Tk[R*72+cn] + c[r]*mm);
      } });
  }

  // ---- ln2 -> Ab[:,0:64] ----
  for (int r=0;r<15;r++){
    float x = (float)Tk[r*72+lane];
    float m = wsum(x)*(1.f/64.f);
    float d = x-m;
    float v = wsum(d*d)*(1.f/64.f);
    Ab[r*136+lane] = (__bf16)(d*(1.0f/sqrtf(v+1e-6f))*a.ln2_s[lane]+a.ln2_b[lane]);
  }

  // ---- slot MLP: m1 -> Bb, m2 -> Ab, m3 -> Tk ----
  { Frag<2> fa = loadA<2>(Ab,136,lane);
    gemmF<2>(fa, ws+W_M1, 8, a.m1_b, lane, [&](int r0,int cn,v4f c){
      #pragma unroll
      for (int r=0;r<4;r++) Bb[(r0+r)*136+cn]=(__bf16)gelu_f(c[r]); }); }
  { Frag<4> fa = loadA<4>(Bb,136,lane);
    gemmF<4>(fa, ws+W_M2, 8, a.m2_b, lane, [&](int r0,int cn,v4f c){
      #pragma unroll
      for (int r=0;r<4;r++) Ab[(r0+r)*136+cn]=(__bf16)gelu_f(c[r]); }); }
  { Frag<4> fa = loadA<4>(Ab,136,lane);
    gemmF<4>(fa, ws+W_M3, 4, a.m3_b, lane, [&](int r0,int cn,v4f c){
      #pragma unroll
      for (int r=0;r<4;r++){
        int R=r0+r; float mm=(R<15)?mf[R]:0.f;
        Tk[R*72+cn] = (__bf16)(((float)Tk[R*72+cn] + c[r]*mm)*mm);
      } }); }

  // ---- ego MLP: e1 -> Bb, e2 -> Ab, e3 -> ECX (rows<3) ----
  { Frag<1> fa = loadA<1>(Eg,40,lane);
    gemmF<1>(fa, ws+W_E1, 8, a.e1_b, lane, [&](int r0,int cn,v4f c){
      #pragma unroll
      for (int r=0;r<4;r++) Bb[(r0+r)*136+cn]=(__bf16)gelu_f(c[r]); }); }
  { Frag<4> fa = loadA<4>(Bb,136,lane);
    gemmF<4>(fa, ws+W_E2, 8, a.e2_b, lane, [&](int r0,int cn,v4f c){
      #pragma unroll
      for (int r=0;r<4;r++) Ab[(r0+r)*136+cn]=(__bf16)gelu_f(c[r]); }); }
  { Frag<4> fa = loadA<4>(Ab,136,lane);
    gemmF<4>(fa, ws+W_E3, 4, a.e3_b, lane, [&](int r0,int cn,v4f c){
      #pragma unroll
      for (int r=0;r<4;r++){
        int R=r0+r;
        if (R<3) ECX[R*64+cn]=(__bf16)c[r];
      } }); }

  // ---- l1 (A = [Tk | ego_ctx] composed in-fragment) -> Bb; l2 -> Ab ----
  {
    Frag<4> fl;
    { const int col=lane&15, quad=lane>>4;
      const __bf16* pt = Tk + (size_t)col*72 + quad*8;
      fl.v[0]=*(const v8bf*)pt; fl.v[1]=*(const v8bf*)(pt+32);
      const __bf16* pe_ = ECX + (size_t)(col/5)*64 + quad*8;
      fl.v[2]=*(const v8bf*)pe_; fl.v[3]=*(const v8bf*)(pe_+32); }
    gemmF<4>(fl, ws+W_L1, 8, a.l1_b, lane, [&](int r0,int cn,v4f c){
      #pragma unroll
      for (int r=0;r<4;r++) Bb[(r0+r)*136+cn]=(__bf16)gelu_f(c[r]); });
  }
  { Frag<4> fa = loadA<4>(Bb,136,lane);
    gemmF<4>(fa, ws+W_L2, 8, a.l2_b, lane, [&](int r0,int cn,v4f c){
      #pragma unroll
      for (int r=0;r<4;r++) Ab[(r0+r)*136+cn]=(__bf16)gelu_f(c[r]); }); }

  // ---- l3 logits + alpha + v_r/v_u ----
  {
    float wA = a.l3_w[lane], wB = a.l3_w[64+lane];
    for (int r=0;r<15;r++){
      float v = (float)Ab[r*136+lane]*wA + (float)Ab[r*136+64+lane]*wB;
      v = wsum(v);
      if (lane==0) lg[r] = v + a.l3_b[0];
    }
  }
  if (lane<3){
    float ml[5], mx=-1e9f;
    #pragma unroll
    for (int i=0;i<5;i++){ ml[i]=(mf[lane*5+i]>0.5f)? lg[lane*5+i] : -1e9f; mx=fmaxf(mx,ml[i]); }
    float den=0.f;
    #pragma unroll
    for (int i=0;i<5;i++){ float e=__expf(ml[i]-mx)*mf[lane*5+i]; alpha[lane*5+i]=e; den+=e; }
    float inv=1.0f/(den+1e-9f);
    #pragma unroll
    for (int i=0;i<5;i++) alpha[lane*5+i]*=inv;
  }
  if (lane<18){
    int tg=lane/6, c=lane-tg*6;
    float v=0.f;
    #pragma unroll
    for (int i=0;i<5;i++) v += alpha[tg*5+i]*Ru[tg*32+i*6+c];
    if (t0+tg<ntok) a.out[(t0+tg)*134+128+c]=v;
  }

  // ---- pooling: kp -> Bb[0:64], vp -> Bb[64:128] (shared Tk fragment) ----
  {
    Frag<2> ft = loadA<2>(Tk,72,lane);
    gemmF<2>(ft, ws+W_PK, 4, a.p_kb, lane, [&](int r0,int cn,v4f c){
      #pragma unroll
      for (int r=0;r<4;r++) Bb[(r0+r)*136+cn]=(__bf16)c[r]; });
    gemmF<2>(ft, ws+W_PV, 4, a.p_vb, lane, [&](int r0,int cn,v4f c){
      #pragma unroll
      for (int r=0;r<4;r++) Bb[(r0+r)*136+64+cn]=(__bf16)c[r]; });
  }

  // ---- pooling attn (3 tok x 4 h = 12 lanes) ----
  if (lane<12){
    int tg=lane>>2, h=lane&3;
    float lgv[5], mx=NEG_INF_F;
    #pragma unroll
    for (int j=0;j<5;j++){
      float kk[16]; load16f(&Bb[(tg*5+j)*136 + h*16], kk);
      float d=0.f;
      #pragma unroll
      for (int dd=0;dd<16;dd++) d += qp[h*16+dd]*kk[dd];
      lgv[j] = (msf[tg*5+j]>0.5f)? d*0.25f : NEG_INF_F;
      mx = fmaxf(mx,lgv[j]);
    }
    float sum=0.f, ex[5];
    #pragma unroll
    for (int j=0;j<5;j++){ ex[j]=__expf(lgv[j]-mx); sum+=ex[j]; }
    float inv=1.0f/sum;
    #pragma unroll
    for (int j=0;j<5;j++) pattn[tg*20+h*5+j]=ex[j]*inv;
  }

  // ---- pooled o -> Po (overlays dead Tk) ----
  for (int it=lane; it<192; it+=64){
    int tg=it>>6, c=it&63, h=c>>4;
    float o=0.f;
    #pragma unroll
    for (int j=0;j<5;j++)
      o += pattn[tg*20+h*5+j]*(float)Bb[(tg*5+j)*136+64+c];
    Po[tg*64+c]=(__bf16)o;
  }

  // ---- p_ow -> Cc (rows<3, x many) ----
  { Frag<2> fa = loadA<2>(Po,64,lane);
    gemmF<2>(fa, ws+W_PO, 4, a.p_ob, lane, [&](int r0,int cn,v4f c){
      #pragma unroll
      for (int r=0;r<4;r++){
        int R=r0+r;
        if (R<3) Cc[R*64+cn]=(__bf16)(c[r]*many[R]);
      } }); }

  // ---- h1 (A = [ego | c | pe] composed in-fragment, K=160) -> Bb ----
  {
    Frag<5> fh;
    { const int col=lane&15, quad=lane>>4;
      fh.v[0]=*(const v8bf*)(Eg + (size_t)col*40 + quad*8);
      const __bf16* pc = Cc + (size_t)col*64 + quad*8;
      fh.v[1]=*(const v8bf*)pc; fh.v[2]=*(const v8bf*)(pc+32);
      const __bf16* pp = Pe + (size_t)col*64 + quad*8;
      fh.v[3]=*(const v8bf*)pp; fh.v[4]=*(const v8bf*)(pp+32); }
    gemmF<5>(fh, ws+W_H1, 8, a.h1_b, lane, [&](int r0,int cn,v4f c){
      #pragma unroll
      for (int r=0;r<4;r++) Bb[(r0+r)*136+cn]=(__bf16)gelu_f(c[r]); });
  }
  // ---- h2 -> Ab ----
  { Frag<4> fa = loadA<4>(Bb,136,lane);
    gemmF<4>(fa, ws+W_H2, 8, a.h2_b, lane, [&](int r0,int cn,v4f c){
      #pragma unroll
      for (int r=0;r<4;r++) Ab[(r0+r)*136+cn]=(__bf16)gelu_f(c[r]); }); }
  // ---- h3 -> out ----
  { Frag<4> fa = loadA<4>(Ab,136,lane);
    gemmF<4>(fa, ws+W_H3, 8, a.h3_b, lane, [&](int r0,int cn,v4f c){
      #pragma unroll
      for (int r=0;r<4;r++){
        int R=r0+r;
        long tk=t0+R;
        if (R<3 && tk<ntok) a.out[tk*134+cn]=c[r];
      } }); }
}

extern "C" void kernel_launch(void* const* d_in, const int* in_sizes, int n_in,
                              void* d_out, int out_size, void* d_ws, size_t ws_size,
                              hipStream_t stream)
{
  P a;
  const float** pp = reinterpret_cast<const float**>(&a);
  for (int i=0;i<50;i++) pp[i] = reinterpret_cast<const float*>(d_in[i]);
  a.out = reinterpret_cast<float*>(d_out);
  int ntok = in_sizes[0] / DOBS;   // 65536

  __bf16* ws = reinterpret_cast<__bf16*>(d_ws);
  hipLaunchKernelGGL(prep_w, dim3(172), dim3(256), 0, stream, a, ws);
  hipLaunchKernelGGL(swarm_mfma, dim3((ntok+11)/12), dim3(256), 0, stream, a, ws, ntok);
}

// Round 6
// 1109.847 us; speedup vs baseline: 1.0977x; 1.0977x over previous
//
#include <hip/hip_runtime.h>
#include <math.h>

// SwarmSetEquivariantTorso — bf16 MFMA, wave-private, zero barriers, 3 blk/CU.
// Block = 256 = 4 independent waves; wave owns 3 tokens (15 slot rows in one
// 16-row M-tile). GEMMs use SWAPPED operands: mfma(A=weight-frag, B=act-frag)
// so D[m=wcol][n=act-row]: each lane holds 4 consecutive output columns of one
// row -> packed b64 epilogue stores. Weights from pre-transposed bf16 image
// W_t[n][k] in d_ws (same image serves both operand roles). LDS alloc kept
// <= 53248 (round-4-proven 3 blocks/CU). gelu = x*sigmoid(2t) exact form.

#define DOBS 198
#define NEG_INF_F (-3.402823466e38f)

typedef __bf16 v8bf __attribute__((ext_vector_type(8)));
typedef __bf16 v4bf __attribute__((ext_vector_type(4)));
typedef float  v4f  __attribute__((ext_vector_type(4)));

struct P {
  const float *obs,*tok_w,*tok_b,*ln1_s,*ln1_b,
    *a1_qw,*a1_qb,*a1_kw,*a1_kb,*a1_vw,*a1_vb,*a1_ow,*a1_ob,
    *ln2_s,*ln2_b,*m1_w,*m1_b,*m2_w,*m2_b,*m3_w,*m3_b,
    *e1_w,*e1_b,*e2_w,*e2_b,*e3_w,*e3_b,
    *l1_w,*l1_b,*l2_w,*l2_b,*l3_w,*l3_b,
    *seed,*p_qw,*p_qb,*p_kw,*p_kb,*p_vw,*p_vb,*p_ow,*p_ob,
    *pr_w,*pr_b,*h1_w,*h1_b,*h2_w,*h2_b,*h3_w,*h3_b;
  float* out;
};
static_assert(sizeof(P) == 51*sizeof(void*), "P layout");

// ws bf16 weight image, W_t[n][k] per matrix (element offsets)
#define W_A1Q 0
#define W_A1K 4096
#define W_A1V 8192
#define W_A1O 12288
#define W_M1  16384
#define W_M2  24576
#define W_M3  40960
#define W_E1  49152
#define W_E2  53248
#define W_E3  69632
#define W_L1  77824
#define W_L2  94208
#define W_PK  110592
#define W_PV  114688
#define W_PO  118784
#define W_H1  122880
#define W_H2  143360
#define W_H3  159744
#define W_END 176128
#define W_QP  176128   // + 128 bf16 slots = 64 f32 (pooling query, precomputed)

__global__ __launch_bounds__(256)
void prep_w(P a, __bf16* ws)
{
  if (blockIdx.x == 172){           // pooling query: qp = seed @ p_qw + p_qb
    int t = threadIdx.x;
    if (t < 64){
      float acc = a.p_qb[t];
      for (int k=0;k<64;k++) acc += a.seed[k]*a.p_qw[k*64+t];
      ((float*)(ws + W_QP))[t] = acc;
    }
    return;
  }
  const float* srcs[18] = {a.a1_qw,a.a1_kw,a.a1_vw,a.a1_ow,a.m1_w,a.m2_w,a.m3_w,
                           a.e1_w,a.e2_w,a.e3_w,a.l1_w,a.l2_w,a.p_kw,a.p_vw,a.p_ow,
                           a.h1_w,a.h2_w,a.h3_w};
  const int Ks[18]   = {64,64,64,64,64,128,128,32,128,128,128,128,64,64,64,160,128,128};
  const int Ns[18]   = {64,64,64,64,128,128,64,128,128,64,128,128,64,64,64,128,128,128};
  const int offs[18] = {W_A1Q,W_A1K,W_A1V,W_A1O,W_M1,W_M2,W_M3,W_E1,W_E2,W_E3,
                        W_L1,W_L2,W_PK,W_PV,W_PO,W_H1,W_H2,W_H3};
  __shared__ float tile[32][33];
  int b = blockIdx.x, m = 0, acc = 0;
  for (; m < 18; m++){
    int t = (Ks[m]/32)*(Ns[m]/32);
    if (b < acc + t) break;
    acc += t;
  }
  int lt = b - acc, K = Ks[m], N = Ns[m];
  int ntile = N/32, kt = lt/ntile, nt = lt%ntile;
  int tx = threadIdx.x & 31, ty = threadIdx.x >> 5;
  const float* S = srcs[m];
  #pragma unroll
  for (int rr=0; rr<32; rr+=8)
    tile[ty+rr][tx] = S[(size_t)(kt*32+ty+rr)*N + nt*32+tx];
  __syncthreads();
  __bf16* D = ws + offs[m];
  #pragma unroll
  for (int rr=0; rr<32; rr+=8)
    D[(size_t)(nt*32+ty+rr)*K + kt*32+tx] = (__bf16)tile[tx][ty+rr];
}

// gelu(x) = 0.5x(1+tanh(t)) = x * sigmoid(2t),  t = 0.79788456(x + 0.044715 x^3)
__device__ __forceinline__ float gelu_f(float x){
  float t = x * fmaf(0.0356774081f, x*x, 0.7978845608f);
  float u = __builtin_amdgcn_exp2f(-2.885390082f * t);   // exp(-2t)
  return x * __builtin_amdgcn_rcpf(1.0f + u);
}

__device__ __forceinline__ float wsum(float v){
  #pragma unroll
  for (int off=32; off>0; off>>=1) v += __shfl_xor(v, off, 64);
  return v;
}

__device__ __forceinline__ void load16f(const __bf16* p, float* f){
  v8bf a = *(const v8bf*)p, b = *(const v8bf*)(p+8);
  #pragma unroll
  for (int i=0;i<8;i++){ f[i]=(float)a[i]; f[8+i]=(float)b[i]; }
}

template<int KT> struct Frag { v8bf v[KT]; };

// act fragment (B-operand): row = lane&15, k-chunk = quad*8
template<int KT>
__device__ __forceinline__ Frag<KT> loadA(const __bf16* A, int lda, int lane){
  Frag<KT> f;
  const __bf16* p = A + (size_t)(lane&15)*lda + (lane>>4)*8;
  #pragma unroll
  for (int kt=0;kt<KT;kt++) f.v[kt] = *(const v8bf*)(p + kt*32);
  return f;
}

// Swapped-operand wave GEMM: D[wcol][arow]; lane holds arow=lane&15,
// wcols = wt*16 + quad*4 + {0..3}. epi(wbase, ar, c).
template<int KT, typename E>
__device__ __forceinline__ void gemmS(const Frag<KT>& fb,
    const __bf16* __restrict__ Wt, int wtiles,
    const float* __restrict__ bias, int lane, E epi)
{
  const int ar = lane&15, quad = lane>>4;
  const int K = KT*32;
  for (int wt=0; wt<wtiles; wt++){
    float4 b4 = *(const float4*)(bias + wt*16 + quad*4);
    v4f c; c[0]=b4.x; c[1]=b4.y; c[2]=b4.z; c[3]=b4.w;
    const __bf16* ap = Wt + (size_t)(wt*16+ar)*K + quad*8;
    #pragma unroll
    for (int kt=0;kt<KT;kt++){
      v8bf av = *(const v8bf*)(ap + kt*32);
      c = __builtin_amdgcn_mfma_f32_16x16x32_bf16(av, fb.v[kt], c, 0, 0, 0);
    }
    epi(wt*16 + quad*4, ar, c);
  }
}

// Per-wave LDS (byte offsets, stride WVSZ=12832):
//  Ab  bf16[16][136] @0      4352  (early: Df f32[3][32])
//  Bb  bf16[16][136] @4352   4352  (early: TOKIN f32[15][12] = 720)
//  TkO               @8704   2304  (OBSf f32[3][120] -> Tk bf16[16][72] -> Po bf16[3][64])
//  Scr               @11008   640  (ATTb bf16[300] -> ECX bf16[3][64] -> {Cc[3][64]@0, pattn f32[60]@384})
//  Pe  bf16[3][64]   @11648   384
//  Eg  bf16[3][40]   @12032   240  (frag overspill -> neighbor/tail, read-only garbage)
//  Ru  f32[3][30]    @12272   368
//  Ax  f32[48]       @12640   192  (mf15|msf15|many3|lga15)
// Total 4*12832 + 1024 tail = 52352 -> alloc <= 53248 -> 3 blocks/CU.
#define WVSZ 12832

__global__ __launch_bounds__(256,3)
void swarm_mfma(P a, const __bf16* __restrict__ ws, int ntok)
{
  __shared__ char smem[4*WVSZ + 1024] __attribute__((aligned(16)));
  const int lane = threadIdx.x & 63;
  const int wv   = threadIdx.x >> 6;
  char* wb = smem + wv*WVSZ;
  __bf16* Ab   = (__bf16*)(wb);
  __bf16* Bb   = (__bf16*)(wb+4352);
  float*  TOKIN= (float*) (wb+4352);
  float*  OBSf = (float*) (wb+8704);
  __bf16* Tk   = (__bf16*)(wb+8704);
  __bf16* Po   = (__bf16*)(wb+8704);
  __bf16* ATTb = (__bf16*)(wb+11008);
  __bf16* ECX  = (__bf16*)(wb+11008);
  __bf16* Cc   = (__bf16*)(wb+11008);
  float*  pattn= (float*) (wb+11008+384);
  __bf16* Pe   = (__bf16*)(wb+11648);
  __bf16* Eg   = (__bf16*)(wb+12032);
  float*  Ru   = (float*) (wb+12272);
  float*  Ax   = (float*) (wb+12640);
  float* mf    = Ax;      // [15]  (mf[15] aliases msf[0] -> harmless pad-row mask)
  float* msf   = Ax+15;   // [15]
  float* many  = Ax+30;   // [3]
  float* lga   = Ax+33;   // [15] logits, then alpha (in-lane read-before-write)

  const long t0 = (long)blockIdx.x*12 + wv*3;

  // ---- P0: obs load ----
  for (int it=lane; it<3*117; it+=64){
    int tg=it/117, c=it-tg*117;
    long gt=t0+tg; if (gt>ntok-1) gt=ntok-1;
    OBSf[tg*120+c] = a.obs[gt*DOBS+c];
  }

  // ---- P1: masks + pair distances ----
  float* Df = (float*)Ab;
  for (int it=lane; it<75; it+=64){
    int tg=it/25, p=it-tg*25, i=p/5, j=p-i*5;
    const float* ob = OBSf + tg*120 + 32;
    float d2=0.f;
    #pragma unroll
    for (int d=0;d<3;d++){
      float ri=ob[15*i+d]; ri = isfinite(ri)?ri:0.f;
      float rj=ob[15*j+d]; rj = isfinite(rj)?rj:0.f;
      float df=ri-rj; d2 += df*df;
    }
    Df[tg*32+p]=sqrtf(d2);
  }
  if (lane<15){
    int tg=lane/5, s=lane-tg*5;
    const float* b = OBSf + tg*120 + 32 + 15*s;
    mf[lane] = (fabsf(b[0])>1e-6f||fabsf(b[1])>1e-6f||fabsf(b[2])>1e-6f)?1.f:0.f;
  }
  if (lane<3){
    float any = mf[lane*5]+mf[lane*5+1]+mf[lane*5+2]+mf[lane*5+3]+mf[lane*5+4];
    float anyf = (any>0.f)?1.f:0.f; many[lane]=anyf;
    #pragma unroll
    for (int i=0;i<5;i++) msf[lane*5+i] = (anyf>0.f)? mf[lane*5+i] : (i==0?1.f:0.f);
  }
  if (lane<15){
    int tg=lane/5, i=lane-tg*5;
    float dmin=1e9f,dsum=0.f,cnt=0.f;
    #pragma unroll
    for (int j=0;j<5;j++){
      if (j!=i && mf[tg*5+i]>0.5f && mf[tg*5+j]>0.5f){
        float dd=Df[tg*32+i*5+j];
        dmin=fminf(dmin,dd); dsum+=dd; cnt+=1.f;
      }
    }
    TOKIN[lane*12+10]=dmin;
    TOKIN[lane*12+11]=(cnt>0.f)? dsum/(cnt+1e-9f) : 0.f;
  }

  // ---- P2: tok_in main, ego, ru, pair_emb ----
  for (int it=lane; it<150; it+=64){
    int tg=it/50, q=it-tg*50, s=q/10, c=q-s*10;
    const float* b = OBSf + tg*120 + 32 + 15*s;
    float v;
    if (c<4)        v=b[11+c];
    else if (c==4)  v=b[9];
    else if (c==5)  v=b[10];
    else if (c<9)   v=b[6+(c-6)];
    else { float a0=b[6],a1=b[7],a2=b[8]; v=sqrtf(a0*a0+a1*a1+a2*a2); }
    TOKIN[(tg*5+s)*12+c]=v;
  }
  for (int it=lane; it<96; it+=64){
    int tg=it>>5, c=it&31;
    Eg[tg*40+c] = (__bf16)OBSf[tg*120+c];
  }
  for (int it=lane; it<90; it+=64){
    int tg=it/30, c=it-tg*30;
    Ru[tg*30+c] = OBSf[tg*120+32+15*(c/6)+(c%6)];
  }
  for (int it=lane; it<192; it+=64){
    int tg=it>>6, c=it&63;
    float acc = a.pr_b[c];
    #pragma unroll
    for (int k=0;k<10;k++) acc += OBSf[tg*120+107+k]*a.pr_w[k*64+c];
    Pe[tg*64+c] = (__bf16)gelu_f(acc);
  }

  // ---- P3: tok embed (fp32 K=12) + mask + ln1; Tk overlays dead OBSf ----
  {
    float w0[12];
    #pragma unroll
    for (int k=0;k<12;k++) w0[k] = a.tok_w[k*64+lane];
    float tb = a.tok_b[lane], s1 = a.ln1_s[lane], b1 = a.ln1_b[lane];
    for (int r=0;r<15;r++){
      const float4* tin = (const float4*)(TOKIN + r*12);
      float4 x0 = tin[0], x1 = tin[1], x2 = tin[2];
      float acc = tb;
      acc = fmaf(x0.x,w0[0],acc); acc = fmaf(x0.y,w0[1],acc);
      acc = fmaf(x0.z,w0[2],acc); acc = fmaf(x0.w,w0[3],acc);
      acc = fmaf(x1.x,w0[4],acc); acc = fmaf(x1.y,w0[5],acc);
      acc = fmaf(x1.z,w0[6],acc); acc = fmaf(x1.w,w0[7],acc);
      acc = fmaf(x2.x,w0[8],acc); acc = fmaf(x2.y,w0[9],acc);
      acc = fmaf(x2.z,w0[10],acc); acc = fmaf(x2.w,w0[11],acc);
      float t = gelu_f(acc)*mf[r];
      Tk[r*72+lane] = (__bf16)t;
      float m = wsum(t)*(1.f/64.f);
      float d = t-m;
      float v = wsum(d*d)*(1.f/64.f);
      Ab[r*136+lane] = (__bf16)(d*(1.0f/sqrtf(v+1e-6f))*s1+b1);
    }
  }

  // ---- QKV (shared act fragment): K->Bb[64:], V->Ab[64:], Q->Bb[0:] ----
  {
    Frag<2> fb = loadA<2>(Ab,136,lane);
    gemmS<2>(fb, ws+W_A1K, 4, a.a1_kb, lane, [&](int wbse,int ar,v4f c){
      v4bf o;
      #pragma unroll
      for (int r=0;r<4;r++) o[r]=(__bf16)c[r];
      *(v4bf*)&Bb[ar*136+64+wbse]=o; });
    gemmS<2>(fb, ws+W_A1V, 4, a.a1_vb, lane, [&](int wbse,int ar,v4f c){
      v4bf o;
      #pragma unroll
      for (int r=0;r<4;r++) o[r]=(__bf16)c[r];
      *(v4bf*)&Ab[ar*136+64+wbse]=o; });
    gemmS<2>(fb, ws+W_A1Q, 4, a.a1_qb, lane, [&](int wbse,int ar,v4f c){
      v4bf o;
      #pragma unroll
      for (int r=0;r<4;r++) o[r]=(__bf16)c[r];
      *(v4bf*)&Bb[ar*136+wbse]=o; });
  }

  // ---- attn weights (3 tok x 4 h x 5 i = 60 lanes) ----
  if (lane<60){
    int tg=lane/20, rem=lane-tg*20, h=rem/5, i=rem-h*5;
    bool mi = msf[tg*5+i]>0.5f;
    float q[16]; load16f(&Bb[(tg*5+i)*136 + h*16], q);
    float lgv[5], mx=NEG_INF_F;
    #pragma unroll
    for (int j=0;j<5;j++){
      float kk[16]; load16f(&Bb[(tg*5+j)*136 + 64 + h*16], kk);
      float d=0.f;
      #pragma unroll
      for (int dd=0;dd<16;dd++) d += q[dd]*kk[dd];
      bool mj = msf[tg*5+j]>0.5f;
      lgv[j] = (mi&&mj)? d*0.25f : NEG_INF_F;
      mx = fmaxf(mx,lgv[j]);
    }
    float sum=0.f, ex[5];
    #pragma unroll
    for (int j=0;j<5;j++){ ex[j]=__expf(lgv[j]-mx); sum+=ex[j]; }
    float inv=1.0f/sum;
    #pragma unroll
    for (int j=0;j<5;j++) ATTb[tg*100+(h*5+i)*5+j]=(__bf16)(ex[j]*inv);
  }

  // ---- o = attn @ V -> Ab[:,0:64] ----
  for (int r=0;r<15;r++){
    int tg=r/5, i=r-tg*5, h=lane>>4;
    float o=0.f;
    #pragma unroll
    for (int j=0;j<5;j++)
      o += (float)ATTb[tg*100+(h*5+i)*5+j]*(float)Ab[(tg*5+j)*136+64+lane];
    Ab[r*136+lane]=(__bf16)o;
  }

  // ---- o-proj + residual -> Tk ----
  { Frag<2> fb = loadA<2>(Ab,136,lane);
    gemmS<2>(fb, ws+W_A1O, 4, a.a1_ob, lane, [&](int wbse,int ar,v4f c){
      float mm = mf[ar];
      v4bf old = *(const v4bf*)&Tk[ar*72+wbse];
      v4bf o;
      #pragma unroll
      for (int r=0;r<4;r++) o[r]=(__bf16)((float)old[r] + c[r]*mm);
      *(v4bf*)&Tk[ar*72+wbse]=o; }); }

  // ---- ln2 -> Ab[:,0:64] ----
  {
    float s2 = a.ln2_s[lane], b2 = a.ln2_b[lane];
    for (int r=0;r<15;r++){
      float x = (float)Tk[r*72+lane];
      float m = wsum(x)*(1.f/64.f);
      float d = x-m;
      float v = wsum(d*d)*(1.f/64.f);
      Ab[r*136+lane] = (__bf16)(d*(1.0f/sqrtf(v+1e-6f))*s2+b2);
    }
  }

  // ---- slot MLP: m1 -> Bb, m2 -> Ab, m3 -> Tk(resid) ----
  { Frag<2> fb = loadA<2>(Ab,136,lane);
    gemmS<2>(fb, ws+W_M1, 8, a.m1_b, lane, [&](int wbse,int ar,v4f c){
      v4bf o;
      #pragma unroll
      for (int r=0;r<4;r++) o[r]=(__bf16)gelu_f(c[r]);
      *(v4bf*)&Bb[ar*136+wbse]=o; }); }
  { Frag<4> fb = loadA<4>(Bb,136,lane);
    gemmS<4>(fb, ws+W_M2, 8, a.m2_b, lane, [&](int wbse,int ar,v4f c){
      v4bf o;
      #pragma unroll
      for (int r=0;r<4;r++) o[r]=(__bf16)gelu_f(c[r]);
      *(v4bf*)&Ab[ar*136+wbse]=o; }); }
  { Frag<4> fb = loadA<4>(Ab,136,lane);
    gemmS<4>(fb, ws+W_M3, 4, a.m3_b, lane, [&](int wbse,int ar,v4f c){
      float mm = mf[ar];
      v4bf old = *(const v4bf*)&Tk[ar*72+wbse];
      v4bf o;
      #pragma unroll
      for (int r=0;r<4;r++) o[r]=(__bf16)(((float)old[r] + c[r]*mm)*mm);
      *(v4bf*)&Tk[ar*72+wbse]=o; }); }

  // ---- ego MLP: e1 -> Bb, e2 -> Ab, e3 -> ECX ----
  { Frag<1> fb = loadA<1>(Eg,40,lane);
    gemmS<1>(fb, ws+W_E1, 8, a.e1_b, lane, [&](int wbse,int ar,v4f c){
      v4bf o;
      #pragma unroll
      for (int r=0;r<4;r++) o[r]=(__bf16)gelu_f(c[r]);
      *(v4bf*)&Bb[ar*136+wbse]=o; }); }
  { Frag<4> fb = loadA<4>(Bb,136,lane);
    gemmS<4>(fb, ws+W_E2, 8, a.e2_b, lane, [&](int wbse,int ar,v4f c){
      v4bf o;
      #pragma unroll
      for (int r=0;r<4;r++) o[r]=(__bf16)gelu_f(c[r]);
      *(v4bf*)&Ab[ar*136+wbse]=o; }); }
  { Frag<4> fb = loadA<4>(Ab,136,lane);
    gemmS<4>(fb, ws+W_E3, 4, a.e3_b, lane, [&](int wbse,int ar,v4f c){
      if (ar<3){
        v4bf o;
        #pragma unroll
        for (int r=0;r<4;r++) o[r]=(__bf16)c[r];
        *(v4bf*)&ECX[ar*64+wbse]=o;
      } }); }

  // ---- l1 (act = [Tk | ego_ctx] composed in-fragment) -> Bb; l2 -> Ab ----
  {
    Frag<4> fl;
    { const int ar=lane&15, quad=lane>>4;
      const __bf16* pt = Tk + (size_t)ar*72 + quad*8;
      fl.v[0]=*(const v8bf*)pt; fl.v[1]=*(const v8bf*)(pt+32);
      const __bf16* pe_ = ECX + (size_t)(ar/5)*64 + quad*8;
      fl.v[2]=*(const v8bf*)pe_; fl.v[3]=*(const v8bf*)(pe_+32); }
    gemmS<4>(fl, ws+W_L1, 8, a.l1_b, lane, [&](int wbse,int ar,v4f c){
      v4bf o;
      #pragma unroll
      for (int r=0;r<4;r++) o[r]=(__bf16)gelu_f(c[r]);
      *(v4bf*)&Bb[ar*136+wbse]=o; });
  }
  { Frag<4> fb = loadA<4>(Bb,136,lane);
    gemmS<4>(fb, ws+W_L2, 8, a.l2_b, lane, [&](int wbse,int ar,v4f c){
      v4bf o;
      #pragma unroll
      for (int r=0;r<4;r++) o[r]=(__bf16)gelu_f(c[r]);
      *(v4bf*)&Ab[ar*136+wbse]=o; }); }

  // ---- l3 logits + alpha + v_r/v_u ----
  {
    float wA = a.l3_w[lane], wB = a.l3_w[64+lane];
    for (int r=0;r<15;r++){
      float v = (float)Ab[r*136+lane]*wA + (float)Ab[r*136+64+lane]*wB;
      v = wsum(v);
      if (lane==0) lga[r] = v + a.l3_b[0];
    }
  }
  if (lane<3){
    float ml[5], mx=-1e9f;
    #pragma unroll
    for (int i=0;i<5;i++){ ml[i]=(mf[lane*5+i]>0.5f)? lga[lane*5+i] : -1e9f; mx=fmaxf(mx,ml[i]); }
    float den=0.f, e[5];
    #pragma unroll
    for (int i=0;i<5;i++){ e[i]=__expf(ml[i]-mx)*mf[lane*5+i]; den+=e[i]; }
    float inv=1.0f/(den+1e-9f);
    #pragma unroll
    for (int i=0;i<5;i++) lga[lane*5+i]=e[i]*inv;
  }
  if (lane<18){
    int tg=lane/6, c=lane-tg*6;
    float v=0.f;
    #pragma unroll
    for (int i=0;i<5;i++) v += lga[tg*5+i]*Ru[tg*30+i*6+c];
    if (t0+tg<ntok) a.out[(t0+tg)*134+128+c]=v;
  }

  // ---- pooling: kp -> Bb[0:64], vp -> Bb[64:128] (shared Tk fragment) ----
  {
    Frag<2> ft = loadA<2>(Tk,72,lane);
    gemmS<2>(ft, ws+W_PK, 4, a.p_kb, lane, [&](int wbse,int ar,v4f c){
      v4bf o;
      #pragma unroll
      for (int r=0;r<4;r++) o[r]=(__bf16)c[r];
      *(v4bf*)&Bb[ar*136+wbse]=o; });
    gemmS<2>(ft, ws+W_PV, 4, a.p_vb, lane, [&](int wbse,int ar,v4f c){
      v4bf o;
      #pragma unroll
      for (int r=0;r<4;r++) o[r]=(__bf16)c[r];
      *(v4bf*)&Bb[ar*136+64+wbse]=o; });
  }

  // ---- pooling attn (qp from ws, precomputed) ----
  if (lane<12){
    const float* qg = (const float*)(ws + W_QP);
    int tg=lane>>2, h=lane&3;
    float q[16];
    #pragma unroll
    for (int dd=0;dd<16;dd++) q[dd]=qg[h*16+dd];
    float lgv[5], mx=NEG_INF_F;
    #pragma unroll
    for (int j=0;j<5;j++){
      float kk[16]; load16f(&Bb[(tg*5+j)*136 + h*16], kk);
      float d=0.f;
      #pragma unroll
      for (int dd=0;dd<16;dd++) d += q[dd]*kk[dd];
      lgv[j] = (msf[tg*5+j]>0.5f)? d*0.25f : NEG_INF_F;
      mx = fmaxf(mx,lgv[j]);
    }
    float sum=0.f, ex[5];
    #pragma unroll
    for (int j=0;j<5;j++){ ex[j]=__expf(lgv[j]-mx); sum+=ex[j]; }
    float inv=1.0f/sum;
    #pragma unroll
    for (int j=0;j<5;j++) pattn[tg*20+h*5+j]=ex[j]*inv;
  }

  // ---- pooled o -> Po (overlays dead Tk rows 0..2) ----
  for (int it=lane; it<192; it+=64){
    int tg=it>>6, c=it&63, h=c>>4;
    float o=0.f;
    #pragma unroll
    for (int j=0;j<5;j++)
      o += pattn[tg*20+h*5+j]*(float)Bb[(tg*5+j)*136+64+c];
    Po[tg*64+c]=(__bf16)o;
  }

  // ---- p_ow -> Cc (rows<3, x many) ----
  { Frag<2> fb = loadA<2>(Po,64,lane);
    gemmS<2>(fb, ws+W_PO, 4, a.p_ob, lane, [&](int wbse,int ar,v4f c){
      if (ar<3){
        float mm = many[ar];
        v4bf o;
        #pragma unroll
        for (int r=0;r<4;r++) o[r]=(__bf16)(c[r]*mm);
        *(v4bf*)&Cc[ar*64+wbse]=o;
      } }); }

  // ---- h1 (act = [ego | c | pe], K=160) -> Bb ----
  {
    Frag<5> fh;
    { const int ar=lane&15, quad=lane>>4;
      fh.v[0]=*(const v8bf*)(Eg + (size_t)ar*40 + quad*8);
      const __bf16* pc = Cc + (size_t)ar*64 + quad*8;
      fh.v[1]=*(const v8bf*)pc; fh.v[2]=*(const v8bf*)(pc+32);
      const __bf16* pp = Pe + (size_t)ar*64 + quad*8;
      fh.v[3]=*(const v8bf*)pp; fh.v[4]=*(const v8bf*)(pp+32); }
    gemmS<5>(fh, ws+W_H1, 8, a.h1_b, lane, [&](int wbse,int ar,v4f c){
      v4bf o;
      #pragma unroll
      for (int r=0;r<4;r++) o[r]=(__bf16)gelu_f(c[r]);
      *(v4bf*)&Bb[ar*136+wbse]=o; });
  }
  // ---- h2 -> Ab ----
  { Frag<4> fb = loadA<4>(Bb,136,lane);
    gemmS<4>(fb, ws+W_H2, 8, a.h2_b, lane, [&](int wbse,int ar,v4f c){
      v4bf o;
      #pragma unroll
      for (int r=0;r<4;r++) o[r]=(__bf16)gelu_f(c[r]);
      *(v4bf*)&Ab[ar*136+wbse]=o; }); }
  // ---- h3 -> out (float2 pairs, 8B-aligned) ----
  { Frag<4> fb = loadA<4>(Ab,136,lane);
    gemmS<4>(fb, ws+W_H3, 8, a.h3_b, lane, [&](int wbse,int ar,v4f c){
      long tk = t0 + ar;
      if (ar<3 && tk<ntok){
        float2* o2 = (float2*)&a.out[tk*134 + wbse];
        o2[0] = make_float2(c[0], c[1]);
        o2[1] = make_float2(c[2], c[3]);
      } }); }
}

extern "C" void kernel_launch(void* const* d_in, const int* in_sizes, int n_in,
                              void* d_out, int out_size, void* d_ws, size_t ws_size,
                              hipStream_t stream)
{
  P a;
  const float** pp = reinterpret_cast<const float**>(&a);
  for (int i=0;i<50;i++) pp[i] = reinterpret_cast<const float*>(d_in[i]);
  a.out = reinterpret_cast<float*>(d_out);
  int ntok = in_sizes[0] / DOBS;   // 65536

  __bf16* ws = reinterpret_cast<__bf16*>(d_ws);
  hipLaunchKernelGGL(prep_w, dim3(173), dim3(256), 0, stream, a, ws);
  hipLaunchKernelGGL(swarm_mfma, dim3((ntok+11)/12), dim3(256), 0, stream, a, ws, ntok);
}

// Round 7
// 1048.140 us; speedup vs baseline: 1.1623x; 1.0589x over previous
//
#include <hip/hip_runtime.h>
#include <math.h>

// SwarmSetEquivariantTorso — bf16 MFMA, wave-private LDS + raw s_barrier pacing.
// Block = 256 = 4 waves; wave owns 3 tokens (15 slot rows in one 16-row M-tile).
// GEMMs: mfma(A=weight-frag from global W_t[n][k] image, B=act-frag from LDS);
// lane holds 4 consecutive output cols of one act-row -> b64 epilogue stores.
// Raw __builtin_amdgcn_s_barrier() before each weight-streaming layer keeps the
// 4 waves in the same layer so weight fragments stay L1-resident (32KB/CU) —
// NO waitcnt-drain (LDS is wave-private; in-wave ordering via compiler waitcnts).
// All reductions parallelized: lane=(quad,row), 16 cols/lane, 2-shuffle sums.

#define DOBS 198
#define NEG_INF_F (-3.402823466e38f)

typedef __bf16 v8bf __attribute__((ext_vector_type(8)));
typedef __bf16 v4bf __attribute__((ext_vector_type(4)));
typedef float  v4f  __attribute__((ext_vector_type(4)));

struct P {
  const float *obs,*tok_w,*tok_b,*ln1_s,*ln1_b,
    *a1_qw,*a1_qb,*a1_kw,*a1_kb,*a1_vw,*a1_vb,*a1_ow,*a1_ob,
    *ln2_s,*ln2_b,*m1_w,*m1_b,*m2_w,*m2_b,*m3_w,*m3_b,
    *e1_w,*e1_b,*e2_w,*e2_b,*e3_w,*e3_b,
    *l1_w,*l1_b,*l2_w,*l2_b,*l3_w,*l3_b,
    *seed,*p_qw,*p_qb,*p_kw,*p_kb,*p_vw,*p_vb,*p_ow,*p_ob,
    *pr_w,*pr_b,*h1_w,*h1_b,*h2_w,*h2_b,*h3_w,*h3_b;
  float* out;
};
static_assert(sizeof(P) == 51*sizeof(void*), "P layout");

// ws bf16 weight image, W_t[n][k] per matrix (element offsets)
#define W_A1Q 0
#define W_A1K 4096
#define W_A1V 8192
#define W_A1O 12288
#define W_M1  16384
#define W_M2  24576
#define W_M3  40960
#define W_E1  49152
#define W_E2  53248
#define W_E3  69632
#define W_L1  77824
#define W_L2  94208
#define W_PK  110592
#define W_PV  114688
#define W_PO  118784
#define W_H1  122880
#define W_H2  143360
#define W_H3  159744
#define W_END 176128
#define W_QP  176128   // + 64 f32 (pooling query, precomputed)

__global__ __launch_bounds__(256)
void prep_w(P a, __bf16* ws)
{
  if (blockIdx.x == 172){
    int t = threadIdx.x;
    if (t < 64){
      float acc = a.p_qb[t];
      for (int k=0;k<64;k++) acc += a.seed[k]*a.p_qw[k*64+t];
      ((float*)(ws + W_QP))[t] = acc;
    }
    return;
  }
  const float* srcs[18] = {a.a1_qw,a.a1_kw,a.a1_vw,a.a1_ow,a.m1_w,a.m2_w,a.m3_w,
                           a.e1_w,a.e2_w,a.e3_w,a.l1_w,a.l2_w,a.p_kw,a.p_vw,a.p_ow,
                           a.h1_w,a.h2_w,a.h3_w};
  const int Ks[18]   = {64,64,64,64,64,128,128,32,128,128,128,128,64,64,64,160,128,128};
  const int Ns[18]   = {64,64,64,64,128,128,64,128,128,64,128,128,64,64,64,128,128,128};
  const int offs[18] = {W_A1Q,W_A1K,W_A1V,W_A1O,W_M1,W_M2,W_M3,W_E1,W_E2,W_E3,
                        W_L1,W_L2,W_PK,W_PV,W_PO,W_H1,W_H2,W_H3};
  __shared__ float tile[32][33];
  int b = blockIdx.x, m = 0, acc = 0;
  for (; m < 18; m++){
    int t = (Ks[m]/32)*(Ns[m]/32);
    if (b < acc + t) break;
    acc += t;
  }
  int lt = b - acc, K = Ks[m], N = Ns[m];
  int ntile = N/32, kt = lt/ntile, nt = lt%ntile;
  int tx = threadIdx.x & 31, ty = threadIdx.x >> 5;
  const float* S = srcs[m];
  #pragma unroll
  for (int rr=0; rr<32; rr+=8)
    tile[ty+rr][tx] = S[(size_t)(kt*32+ty+rr)*N + nt*32+tx];
  __syncthreads();
  __bf16* D = ws + offs[m];
  #pragma unroll
  for (int rr=0; rr<32; rr+=8)
    D[(size_t)(nt*32+ty+rr)*K + kt*32+tx] = (__bf16)tile[tx][ty+rr];
}

// gelu(x) = x * sigmoid(2t),  t = 0.79788456(x + 0.044715 x^3)  (exact tanh form)
__device__ __forceinline__ float gelu_f(float x){
  float t = x * fmaf(0.0356774081f, x*x, 0.7978845608f);
  float u = __builtin_amdgcn_exp2f(-2.885390082f * t);
  return x * __builtin_amdgcn_rcpf(1.0f + u);
}

__device__ __forceinline__ void load16f(const __bf16* p, float* f){
  v8bf a = *(const v8bf*)p, b = *(const v8bf*)(p+8);
  #pragma unroll
  for (int i=0;i<8;i++){ f[i]=(float)a[i]; f[8+i]=(float)b[i]; }
}

// Parallel layernorm over 64 cols: lane=(quad,ar) covers row ar, cols quad*16..+15.
// 4 shuffles total for all 16 rows (vs 12 per row serially).
__device__ __forceinline__ void ln_par(const __bf16* src, int ss, __bf16* dst, int ds_,
                                       const float* __restrict__ sc,
                                       const float* __restrict__ bi, int lane){
  const int ar = lane&15, quad = lane>>4;
  float x[16];
  load16f(src + (size_t)ar*ss + quad*16, x);
  float s = 0.f;
  #pragma unroll
  for (int i=0;i<16;i++) s += x[i];
  s += __shfl_xor(s,16,64); s += __shfl_xor(s,32,64);
  float m = s*(1.f/64.f);
  float q = 0.f;
  #pragma unroll
  for (int i=0;i<16;i++){ float d=x[i]-m; q = fmaf(d,d,q); }
  q += __shfl_xor(q,16,64); q += __shfl_xor(q,32,64);
  float rs = __builtin_amdgcn_rsqf(q*(1.f/64.f)+1e-6f);
  v8bf o0, o1;
  #pragma unroll
  for (int i=0;i<8;i++){
    o0[i] = (__bf16)((x[i]  -m)*rs*sc[quad*16+i]   + bi[quad*16+i]);
    o1[i] = (__bf16)((x[8+i]-m)*rs*sc[quad*16+8+i] + bi[quad*16+8+i]);
  }
  *(v8bf*)(dst + (size_t)ar*ds_ + quad*16)     = o0;
  *(v8bf*)(dst + (size_t)ar*ds_ + quad*16 + 8) = o1;
}

template<int KT> struct Frag { v8bf v[KT]; };

// act fragment (B-operand): row = lane&15, k-chunk = quad*8
template<int KT>
__device__ __forceinline__ Frag<KT> loadA(const __bf16* A, int lda, int lane){
  Frag<KT> f;
  const __bf16* p = A + (size_t)(lane&15)*lda + (lane>>4)*8;
  #pragma unroll
  for (int kt=0;kt<KT;kt++) f.v[kt] = *(const v8bf*)(p + kt*32);
  return f;
}

// Swapped-operand wave GEMM: out[arow][wcol]; lane holds arow=lane&15,
// wcols = wt*16 + quad*4 + {0..3}. epi(wbase, ar, c).
template<int KT, typename E>
__device__ __forceinline__ void gemmS(const Frag<KT>& fb,
    const __bf16* __restrict__ Wt, int wtiles,
    const float* __restrict__ bias, int lane, E epi)
{
  const int ar = lane&15, quad = lane>>4;
  const int K = KT*32;
  for (int wt=0; wt<wtiles; wt++){
    float4 b4 = *(const float4*)(bias + wt*16 + quad*4);
    v4f c; c[0]=b4.x; c[1]=b4.y; c[2]=b4.z; c[3]=b4.w;
    const __bf16* ap = Wt + (size_t)(wt*16+ar)*K + quad*8;
    #pragma unroll
    for (int kt=0;kt<KT;kt++){
      v8bf av = *(const v8bf*)(ap + kt*32);
      c = __builtin_amdgcn_mfma_f32_16x16x32_bf16(av, fb.v[kt], c, 0, 0, 0);
    }
    epi(wt*16 + quad*4, ar, c);
  }
}

#define PACE() __builtin_amdgcn_s_barrier()

// Per-wave LDS (byte offsets, stride WVSZ=12832) — same map as round 6.
#define WVSZ 12832

__global__ __launch_bounds__(256,3)
void swarm_mfma(P a, const __bf16* __restrict__ ws, int ntok)
{
  __shared__ char smem[4*WVSZ + 1024] __attribute__((aligned(16)));
  const int lane = threadIdx.x & 63;
  const int wv   = threadIdx.x >> 6;
  char* wb = smem + wv*WVSZ;
  __bf16* Ab   = (__bf16*)(wb);
  __bf16* Bb   = (__bf16*)(wb+4352);
  float*  TOKIN= (float*) (wb+4352);
  float*  OBSf = (float*) (wb+8704);
  __bf16* Tk   = (__bf16*)(wb+8704);
  __bf16* Po   = (__bf16*)(wb+8704);
  __bf16* ATTb = (__bf16*)(wb+11008);
  __bf16* ECX  = (__bf16*)(wb+11008);
  __bf16* Cc   = (__bf16*)(wb+11008);
  float*  pattn= (float*) (wb+11008+384);
  __bf16* Pe   = (__bf16*)(wb+11648);
  __bf16* Eg   = (__bf16*)(wb+12032);
  float*  Ru   = (float*) (wb+12272);
  float*  Ax   = (float*) (wb+12640);
  float* mf    = Ax;      // [15] (mf[15] aliases msf[0] -> pad-row mask, harmless)
  float* msf   = Ax+15;   // [15]
  float* many  = Ax+30;   // [3]
  float* lga   = Ax+33;   // [15]

  const long t0 = (long)blockIdx.x*12 + wv*3;

  // ---- P0: obs load ----
  for (int it=lane; it<3*117; it+=64){
    int tg=it/117, c=it-tg*117;
    long gt=t0+tg; if (gt>ntok-1) gt=ntok-1;
    OBSf[tg*120+c] = a.obs[gt*DOBS+c];
  }

  // ---- P1: masks + pair distances ----
  float* Df = (float*)Ab;
  for (int it=lane; it<75; it+=64){
    int tg=it/25, p=it-tg*25, i=p/5, j=p-i*5;
    const float* ob = OBSf + tg*120 + 32;
    float d2=0.f;
    #pragma unroll
    for (int d=0;d<3;d++){
      float ri=ob[15*i+d]; ri = isfinite(ri)?ri:0.f;
      float rj=ob[15*j+d]; rj = isfinite(rj)?rj:0.f;
      float df=ri-rj; d2 += df*df;
    }
    Df[tg*32+p]=sqrtf(d2);
  }
  if (lane<15){
    int tg=lane/5, s=lane-tg*5;
    const float* b = OBSf + tg*120 + 32 + 15*s;
    mf[lane] = (fabsf(b[0])>1e-6f||fabsf(b[1])>1e-6f||fabsf(b[2])>1e-6f)?1.f:0.f;
  }
  if (lane<3){
    float any = mf[lane*5]+mf[lane*5+1]+mf[lane*5+2]+mf[lane*5+3]+mf[lane*5+4];
    float anyf = (any>0.f)?1.f:0.f; many[lane]=anyf;
    #pragma unroll
    for (int i=0;i<5;i++) msf[lane*5+i] = (anyf>0.f)? mf[lane*5+i] : (i==0?1.f:0.f);
  }
  if (lane<15){
    int tg=lane/5, i=lane-tg*5;
    float dmin=1e9f,dsum=0.f,cnt=0.f;
    #pragma unroll
    for (int j=0;j<5;j++){
      if (j!=i && mf[tg*5+i]>0.5f && mf[tg*5+j]>0.5f){
        float dd=Df[tg*32+i*5+j];
        dmin=fminf(dmin,dd); dsum+=dd; cnt+=1.f;
      }
    }
    TOKIN[lane*12+10]=dmin;
    TOKIN[lane*12+11]=(cnt>0.f)? dsum/(cnt+1e-9f) : 0.f;
  }

  // ---- P2: tok_in main, ego, ru, pair_emb ----
  for (int it=lane; it<150; it+=64){
    int tg=it/50, q=it-tg*50, s=q/10, c=q-s*10;
    const float* b = OBSf + tg*120 + 32 + 15*s;
    float v;
    if (c<4)        v=b[11+c];
    else if (c==4)  v=b[9];
    else if (c==5)  v=b[10];
    else if (c<9)   v=b[6+(c-6)];
    else { float a0=b[6],a1=b[7],a2=b[8]; v=sqrtf(a0*a0+a1*a1+a2*a2); }
    TOKIN[(tg*5+s)*12+c]=v;
  }
  for (int it=lane; it<96; it+=64){
    int tg=it>>5, c=it&31;
    Eg[tg*40+c] = (__bf16)OBSf[tg*120+c];
  }
  for (int it=lane; it<90; it+=64){
    int tg=it/30, c=it-tg*30;
    Ru[tg*30+c] = OBSf[tg*120+32+15*(c/6)+(c%6)];
  }
  for (int it=lane; it<192; it+=64){
    int tg=it>>6, c=it&63;
    float acc = a.pr_b[c];
    #pragma unroll
    for (int k=0;k<10;k++) acc += OBSf[tg*120+107+k]*a.pr_w[k*64+c];
    Pe[tg*64+c] = (__bf16)gelu_f(acc);
  }

  // ---- P3: tok embed (fp32 K=12) + mask -> Tk (no inline LN) ----
  {
    float w0[12];
    #pragma unroll
    for (int k=0;k<12;k++) w0[k] = a.tok_w[k*64+lane];
    float tb = a.tok_b[lane];
    for (int r=0;r<15;r++){
      const float4* tin = (const float4*)(TOKIN + r*12);
      float4 x0 = tin[0], x1 = tin[1], x2 = tin[2];
      float acc = tb;
      acc = fmaf(x0.x,w0[0],acc); acc = fmaf(x0.y,w0[1],acc);
      acc = fmaf(x0.z,w0[2],acc); acc = fmaf(x0.w,w0[3],acc);
      acc = fmaf(x1.x,w0[4],acc); acc = fmaf(x1.y,w0[5],acc);
      acc = fmaf(x1.z,w0[6],acc); acc = fmaf(x1.w,w0[7],acc);
      acc = fmaf(x2.x,w0[8],acc); acc = fmaf(x2.y,w0[9],acc);
      acc = fmaf(x2.z,w0[10],acc); acc = fmaf(x2.w,w0[11],acc);
      Tk[r*72+lane] = (__bf16)(gelu_f(acc)*mf[r]);
    }
  }
  // ---- ln1 (parallel) -> Ab[:,0:64] ----
  ln_par(Tk,72, Ab,136, a.ln1_s, a.ln1_b, lane);

  PACE();
  // ---- QKV (shared act fragment): K->Bb[64:], V->Ab[64:], Q->Bb[0:] ----
  {
    Frag<2> fb = loadA<2>(Ab,136,lane);
    gemmS<2>(fb, ws+W_A1K, 4, a.a1_kb, lane, [&](int wbse,int ar,v4f c){
      v4bf o;
      #pragma unroll
      for (int r=0;r<4;r++) o[r]=(__bf16)c[r];
      *(v4bf*)&Bb[ar*136+64+wbse]=o; });
    gemmS<2>(fb, ws+W_A1V, 4, a.a1_vb, lane, [&](int wbse,int ar,v4f c){
      v4bf o;
      #pragma unroll
      for (int r=0;r<4;r++) o[r]=(__bf16)c[r];
      *(v4bf*)&Ab[ar*136+64+wbse]=o; });
    gemmS<2>(fb, ws+W_A1Q, 4, a.a1_qb, lane, [&](int wbse,int ar,v4f c){
      v4bf o;
      #pragma unroll
      for (int r=0;r<4;r++) o[r]=(__bf16)c[r];
      *(v4bf*)&Bb[ar*136+wbse]=o; });
  }

  // ---- attn weights (3 tok x 4 h x 5 i = 60 lanes) ----
  if (lane<60){
    int tg=lane/20, rem=lane-tg*20, h=rem/5, i=rem-h*5;
    bool mi = msf[tg*5+i]>0.5f;
    float q[16]; load16f(&Bb[(tg*5+i)*136 + h*16], q);
    float lgv[5], mx=NEG_INF_F;
    #pragma unroll
    for (int j=0;j<5;j++){
      float kk[16]; load16f(&Bb[(tg*5+j)*136 + 64 + h*16], kk);
      float d=0.f;
      #pragma unroll
      for (int dd=0;dd<16;dd++) d += q[dd]*kk[dd];
      bool mj = msf[tg*5+j]>0.5f;
      lgv[j] = (mi&&mj)? d*0.25f : NEG_INF_F;
      mx = fmaxf(mx,lgv[j]);
    }
    float sum=0.f, ex[5];
    #pragma unroll
    for (int j=0;j<5;j++){ ex[j]=__expf(lgv[j]-mx); sum+=ex[j]; }
    float inv=1.0f/sum;
    #pragma unroll
    for (int j=0;j<5;j++) ATTb[tg*100+(h*5+i)*5+j]=(__bf16)(ex[j]*inv);
  }

  // ---- o = attn @ V -> Ab[:,0:64] (V hoisted per token-group) ----
  {
    int h = lane>>4;
    #pragma unroll
    for (int tg=0; tg<3; tg++){
      float v5[5];
      #pragma unroll
      for (int j=0;j<5;j++) v5[j] = (float)Ab[(tg*5+j)*136+64+lane];
      #pragma unroll
      for (int i=0;i<5;i++){
        float o=0.f;
        #pragma unroll
        for (int j=0;j<5;j++) o += (float)ATTb[tg*100+(h*5+i)*5+j]*v5[j];
        Ab[(tg*5+i)*136+lane]=(__bf16)o;
      }
    }
  }

  PACE();
  // ---- o-proj + residual -> Tk ----
  { Frag<2> fb = loadA<2>(Ab,136,lane);
    gemmS<2>(fb, ws+W_A1O, 4, a.a1_ob, lane, [&](int wbse,int ar,v4f c){
      float mm = mf[ar];
      v4bf old = *(const v4bf*)&Tk[ar*72+wbse];
      v4bf o;
      #pragma unroll
      for (int r=0;r<4;r++) o[r]=(__bf16)((float)old[r] + c[r]*mm);
      *(v4bf*)&Tk[ar*72+wbse]=o; }); }

  // ---- ln2 (parallel) -> Ab[:,0:64] ----
  ln_par(Tk,72, Ab,136, a.ln2_s, a.ln2_b, lane);

  PACE();
  // ---- slot MLP: m1 -> Bb, m2 -> Ab, m3 -> Tk(resid) ----
  { Frag<2> fb = loadA<2>(Ab,136,lane);
    gemmS<2>(fb, ws+W_M1, 8, a.m1_b, lane, [&](int wbse,int ar,v4f c){
      v4bf o;
      #pragma unroll
      for (int r=0;r<4;r++) o[r]=(__bf16)gelu_f(c[r]);
      *(v4bf*)&Bb[ar*136+wbse]=o; }); }
  PACE();
  { Frag<4> fb = loadA<4>(Bb,136,lane);
    gemmS<4>(fb, ws+W_M2, 8, a.m2_b, lane, [&](int wbse,int ar,v4f c){
      v4bf o;
      #pragma unroll
      for (int r=0;r<4;r++) o[r]=(__bf16)gelu_f(c[r]);
      *(v4bf*)&Ab[ar*136+wbse]=o; }); }
  PACE();
  { Frag<4> fb = loadA<4>(Ab,136,lane);
    gemmS<4>(fb, ws+W_M3, 4, a.m3_b, lane, [&](int wbse,int ar,v4f c){
      float mm = mf[ar];
      v4bf old = *(const v4bf*)&Tk[ar*72+wbse];
      v4bf o;
      #pragma unroll
      for (int r=0;r<4;r++) o[r]=(__bf16)(((float)old[r] + c[r]*mm)*mm);
      *(v4bf*)&Tk[ar*72+wbse]=o; }); }

  // ---- ego MLP: e1 -> Bb, e2 -> Ab, e3 -> ECX ----
  { Frag<1> fb = loadA<1>(Eg,40,lane);
    gemmS<1>(fb, ws+W_E1, 8, a.e1_b, lane, [&](int wbse,int ar,v4f c){
      v4bf o;
      #pragma unroll
      for (int r=0;r<4;r++) o[r]=(__bf16)gelu_f(c[r]);
      *(v4bf*)&Bb[ar*136+wbse]=o; }); }
  PACE();
  { Frag<4> fb = loadA<4>(Bb,136,lane);
    gemmS<4>(fb, ws+W_E2, 8, a.e2_b, lane, [&](int wbse,int ar,v4f c){
      v4bf o;
      #pragma unroll
      for (int r=0;r<4;r++) o[r]=(__bf16)gelu_f(c[r]);
      *(v4bf*)&Ab[ar*136+wbse]=o; }); }
  PACE();
  { Frag<4> fb = loadA<4>(Ab,136,lane);
    gemmS<4>(fb, ws+W_E3, 4, a.e3_b, lane, [&](int wbse,int ar,v4f c){
      if (ar<3){
        v4bf o;
        #pragma unroll
        for (int r=0;r<4;r++) o[r]=(__bf16)c[r];
        *(v4bf*)&ECX[ar*64+wbse]=o;
      } }); }

  PACE();
  // ---- l1 (act = [Tk | ego_ctx] composed in-fragment) -> Bb; l2 -> Ab ----
  {
    Frag<4> fl;
    { const int ar=lane&15, quad=lane>>4;
      const __bf16* pt = Tk + (size_t)ar*72 + quad*8;
      fl.v[0]=*(const v8bf*)pt; fl.v[1]=*(const v8bf*)(pt+32);
      const __bf16* pe_ = ECX + (size_t)(ar/5)*64 + quad*8;
      fl.v[2]=*(const v8bf*)pe_; fl.v[3]=*(const v8bf*)(pe_+32); }
    gemmS<4>(fl, ws+W_L1, 8, a.l1_b, lane, [&](int wbse,int ar,v4f c){
      v4bf o;
      #pragma unroll
      for (int r=0;r<4;r++) o[r]=(__bf16)gelu_f(c[r]);
      *(v4bf*)&Bb[ar*136+wbse]=o; });
  }
  PACE();
  { Frag<4> fb = loadA<4>(Bb,136,lane);
    gemmS<4>(fb, ws+W_L2, 8, a.l2_b, lane, [&](int wbse,int ar,v4f c){
      v4bf o;
      #pragma unroll
      for (int r=0;r<4;r++) o[r]=(__bf16)gelu_f(c[r]);
      *(v4bf*)&Ab[ar*136+wbse]=o; }); }

  // ---- l3 logits (parallel partial-dot: lane=(quad,ar), 32 cols each) ----
  {
    const int ar = lane&15, quad = lane>>4;
    float x[16], y[16];
    load16f(&Ab[ar*136 + quad*32], x);
    load16f(&Ab[ar*136 + quad*32 + 16], y);
    const float* w = a.l3_w + quad*32;
    float p = 0.f;
    #pragma unroll
    for (int i=0;i<16;i++) p = fmaf(x[i], w[i], p);
    #pragma unroll
    for (int i=0;i<16;i++) p = fmaf(y[i], w[16+i], p);
    p += __shfl_xor(p,16,64); p += __shfl_xor(p,32,64);
    if (lane<15) lga[lane] = p + a.l3_b[0];
  }
  // ---- alpha + v_r/v_u ----
  if (lane<3){
    float ml[5], mx=-1e9f;
    #pragma unroll
    for (int i=0;i<5;i++){ ml[i]=(mf[lane*5+i]>0.5f)? lga[lane*5+i] : -1e9f; mx=fmaxf(mx,ml[i]); }
    float den=0.f, e[5];
    #pragma unroll
    for (int i=0;i<5;i++){ e[i]=__expf(ml[i]-mx)*mf[lane*5+i]; den+=e[i]; }
    float inv=1.0f/(den+1e-9f);
    #pragma unroll
    for (int i=0;i<5;i++) lga[lane*5+i]=e[i]*inv;
  }
  if (lane<18){
    int tg=lane/6, c=lane-tg*6;
    float v=0.f;
    #pragma unroll
    for (int i=0;i<5;i++) v += lga[tg*5+i]*Ru[tg*30+i*6+c];
    if (t0+tg<ntok) a.out[(t0+tg)*134+128+c]=v;
  }

  PACE();
  // ---- pooling: kp -> Bb[0:64], vp -> Bb[64:128] (shared Tk fragment) ----
  {
    Frag<2> ft = loadA<2>(Tk,72,lane);
    gemmS<2>(ft, ws+W_PK, 4, a.p_kb, lane, [&](int wbse,int ar,v4f c){
      v4bf o;
      #pragma unroll
      for (int r=0;r<4;r++) o[r]=(__bf16)c[r];
      *(v4bf*)&Bb[ar*136+wbse]=o; });
    gemmS<2>(ft, ws+W_PV, 4, a.p_vb, lane, [&](int wbse,int ar,v4f c){
      v4bf o;
      #pragma unroll
      for (int r=0;r<4;r++) o[r]=(__bf16)c[r];
      *(v4bf*)&Bb[ar*136+64+wbse]=o; });
  }

  // ---- pooling attn (qp precomputed in ws) ----
  if (lane<12){
    const float* qg = (const float*)(ws + W_QP);
    int tg=lane>>2, h=lane&3;
    float q[16];
    #pragma unroll
    for (int dd=0;dd<16;dd++) q[dd]=qg[h*16+dd];
    float lgv[5], mx=NEG_INF_F;
    #pragma unroll
    for (int j=0;j<5;j++){
      float kk[16]; load16f(&Bb[(tg*5+j)*136 + h*16], kk);
      float d=0.f;
      #pragma unroll
      for (int dd=0;dd<16;dd++) d += q[dd]*kk[dd];
      lgv[j] = (msf[tg*5+j]>0.5f)? d*0.25f : NEG_INF_F;
      mx = fmaxf(mx,lgv[j]);
    }
    float sum=0.f, ex[5];
    #pragma unroll
    for (int j=0;j<5;j++){ ex[j]=__expf(lgv[j]-mx); sum+=ex[j]; }
    float inv=1.0f/sum;
    #pragma unroll
    for (int j=0;j<5;j++) pattn[tg*20+h*5+j]=ex[j]*inv;
  }

  // ---- pooled o -> Po (overlays dead Tk rows 0..2) ----
  for (int it=lane; it<192; it+=64){
    int tg=it>>6, c=it&63, h=c>>4;
    float o=0.f;
    #pragma unroll
    for (int j=0;j<5;j++)
      o += pattn[tg*20+h*5+j]*(float)Bb[(tg*5+j)*136+64+c];
    Po[tg*64+c]=(__bf16)o;
  }

  PACE();
  // ---- p_ow -> Cc (rows<3, x many) ----
  { Frag<2> fb = loadA<2>(Po,64,lane);
    gemmS<2>(fb, ws+W_PO, 4, a.p_ob, lane, [&](int wbse,int ar,v4f c){
      if (ar<3){
        float mm = many[ar];
        v4bf o;
        #pragma unroll
        for (int r=0;r<4;r++) o[r]=(__bf16)(c[r]*mm);
        *(v4bf*)&Cc[ar*64+wbse]=o;
      } }); }

  PACE();
  // ---- h1 (act = [ego | c | pe], K=160) -> Bb ----
  {
    Frag<5> fh;
    { const int ar=lane&15, quad=lane>>4;
      fh.v[0]=*(const v8bf*)(Eg + (size_t)ar*40 + quad*8);
      const __bf16* pc = Cc + (size_t)ar*64 + quad*8;
      fh.v[1]=*(const v8bf*)pc; fh.v[2]=*(const v8bf*)(pc+32);
      const __bf16* pp = Pe + (size_t)ar*64 + quad*8;
      fh.v[3]=*(const v8bf*)pp; fh.v[4]=*(const v8bf*)(pp+32); }
    gemmS<5>(fh, ws+W_H1, 8, a.h1_b, lane, [&](int wbse,int ar,v4f c){
      v4bf o;
      #pragma unroll
      for (int r=0;r<4;r++) o[r]=(__bf16)gelu_f(c[r]);
      *(v4bf*)&Bb[ar*136+wbse]=o; });
  }
  PACE();
  // ---- h2 -> Ab ----
  { Frag<4> fb = loadA<4>(Bb,136,lane);
    gemmS<4>(fb, ws+W_H2, 8, a.h2_b, lane, [&](int wbse,int ar,v4f c){
      v4bf o;
      #pragma unroll
      for (int r=0;r<4;r++) o[r]=(__bf16)gelu_f(c[r]);
      *(v4bf*)&Ab[ar*136+wbse]=o; }); }
  PACE();
  // ---- h3 -> out (float2 pairs, 8B-aligned) ----
  { Frag<4> fb = loadA<4>(Ab,136,lane);
    gemmS<4>(fb, ws+W_H3, 8, a.h3_b, lane, [&](int wbse,int ar,v4f c){
      long tk = t0 + ar;
      if (ar<3 && tk<ntok){
        float2* o2 = (float2*)&a.out[tk*134 + wbse];
        o2[0] = make_float2(c[0], c[1]);
        o2[1] = make_float2(c[2], c[3]);
      } }); }
}

extern "C" void kernel_launch(void* const* d_in, const int* in_sizes, int n_in,
                              void* d_out, int out_size, void* d_ws, size_t ws_size,
                              hipStream_t stream)
{
  P a;
  const float** pp = reinterpret_cast<const float**>(&a);
  for (int i=0;i<50;i++) pp[i] = reinterpret_cast<const float*>(d_in[i]);
  a.out = reinterpret_cast<float*>(d_out);
  int ntok = in_sizes[0] / DOBS;   // 65536

  __bf16* ws = reinterpret_cast<__bf16*>(d_ws);
  hipLaunchKernelGGL(prep_w, dim3(173), dim3(256), 0, stream, a, ws);
  hipLaunchKernelGGL(swarm_mfma, dim3((ntok+11)/12), dim3(256), 0, stream, a, ws, ntok);
}

// Round 9
// 508.548 us; speedup vs baseline: 2.3955x; 2.0610x over previous
//
#include <hip/hip_runtime.h>
#include <math.h>

// SwarmSetEquivariantTorso — bf16 MFMA, N-SPLIT block-cooperative GEMMs.
// Block = 256 threads / 4 waves / 12 tokens (60 slot rows = 4 M-tiles).
// Every GEMM: wave wv owns N-tile columns [wv*NTPW, (wv+1)*NTPW); loops all
// M-tiles. Weight fragments (A-operand, from pre-transposed bf16 W_t[n][k]
// image in d_ws) are loaded EXACTLY ONCE per block and reused across M-tiles
// in registers; act fragments (B-operand) come from shared LDS. Token-level
// layers run once per block (M=1 tile). __syncthreads between layers.
// Glue: parallel LN/l3 (2-shuffle reductions), fast exact gelu, qp precomputed.

#define DOBS 198
#define NEG_INF_F (-3.402823466e38f)

typedef __bf16 v8bf __attribute__((ext_vector_type(8)));
typedef __bf16 v4bf __attribute__((ext_vector_type(4)));
typedef float  v4f  __attribute__((ext_vector_type(4)));

struct P {
  const float *obs,*tok_w,*tok_b,*ln1_s,*ln1_b,
    *a1_qw,*a1_qb,*a1_kw,*a1_kb,*a1_vw,*a1_vb,*a1_ow,*a1_ob,
    *ln2_s,*ln2_b,*m1_w,*m1_b,*m2_w,*m2_b,*m3_w,*m3_b,
    *e1_w,*e1_b,*e2_w,*e2_b,*e3_w,*e3_b,
    *l1_w,*l1_b,*l2_w,*l2_b,*l3_w,*l3_b,
    *seed,*p_qw,*p_qb,*p_kw,*p_kb,*p_vw,*p_vb,*p_ow,*p_ob,
    *pr_w,*pr_b,*h1_w,*h1_b,*h2_w,*h2_b,*h3_w,*h3_b;
  float* out;
};
static_assert(sizeof(P) == 51*sizeof(void*), "P layout");

// ws bf16 weight image, W_t[n][k] per matrix (element offsets)
#define W_A1Q 0
#define W_A1K 4096
#define W_A1V 8192
#define W_A1O 12288
#define W_M1  16384
#define W_M2  24576
#define W_M3  40960
#define W_E1  49152
#define W_E2  53248
#define W_E3  69632
#define W_L1  77824
#define W_L2  94208
#define W_PK  110592
#define W_PV  114688
#define W_PO  118784
#define W_H1  122880
#define W_H2  143360
#define W_H3  159744
#define W_END 176128
#define W_QP  176128   // + 64 f32 (pooling query, precomputed)

__global__ __launch_bounds__(256)
void prep_w(P a, __bf16* ws)
{
  if (blockIdx.x == 172){
    int t = threadIdx.x;
    if (t < 64){
      float acc = a.p_qb[t];
      for (int k=0;k<64;k++) acc += a.seed[k]*a.p_qw[k*64+t];
      ((float*)(ws + W_QP))[t] = acc;
    }
    return;
  }
  const float* srcs[18] = {a.a1_qw,a.a1_kw,a.a1_vw,a.a1_ow,a.m1_w,a.m2_w,a.m3_w,
                           a.e1_w,a.e2_w,a.e3_w,a.l1_w,a.l2_w,a.p_kw,a.p_vw,a.p_ow,
                           a.h1_w,a.h2_w,a.h3_w};
  const int Ks[18]   = {64,64,64,64,64,128,128,32,128,128,128,128,64,64,64,160,128,128};
  const int Ns[18]   = {64,64,64,64,128,128,64,128,128,64,128,128,64,64,64,128,128,128};
  const int offs[18] = {W_A1Q,W_A1K,W_A1V,W_A1O,W_M1,W_M2,W_M3,W_E1,W_E2,W_E3,
                        W_L1,W_L2,W_PK,W_PV,W_PO,W_H1,W_H2,W_H3};
  __shared__ float tile[32][33];
  int b = blockIdx.x, m = 0, acc = 0;
  for (; m < 18; m++){
    int t = (Ks[m]/32)*(Ns[m]/32);
    if (b < acc + t) break;
    acc += t;
  }
  int lt = b - acc, K = Ks[m], N = Ns[m];
  int ntile = N/32, kt = lt/ntile, nt = lt%ntile;
  int tx = threadIdx.x & 31, ty = threadIdx.x >> 5;
  const float* S = srcs[m];
  #pragma unroll
  for (int rr=0; rr<32; rr+=8)
    tile[ty+rr][tx] = S[(size_t)(kt*32+ty+rr)*N + nt*32+tx];
  __syncthreads();
  __bf16* D = ws + offs[m];
  #pragma unroll
  for (int rr=0; rr<32; rr+=8)
    D[(size_t)(nt*32+ty+rr)*K + kt*32+tx] = (__bf16)tile[tx][ty+rr];
}

// gelu(x) = x * sigmoid(2t),  t = 0.79788456(x + 0.044715 x^3)  (exact tanh form)
__device__ __forceinline__ float gelu_f(float x){
  float t = x * fmaf(0.0356774081f, x*x, 0.7978845608f);
  float u = __builtin_amdgcn_exp2f(-2.885390082f * t);
  return x * __builtin_amdgcn_rcpf(1.0f + u);
}

__device__ __forceinline__ void load16f(const __bf16* p, float* f){
  v8bf a = *(const v8bf*)p, b = *(const v8bf*)(p+8);
  #pragma unroll
  for (int i=0;i<8;i++){ f[i]=(float)a[i]; f[8+i]=(float)b[i]; }
}

// N-split block GEMM: D[60+pad x N] = act @ W + bias.
// Wave wv owns N-tiles wt = wv*NTPW..+NTPW-1; weight frags loaded once,
// reused across MT M-tiles. la(mt,kt,ar,quad) -> v8bf act fragment piece.
// epi(wbase, mt, ar, c): D rows mt*16+ar, cols wbase..wbase+3.
template<int KT,int MT,int NTPW,typename LA,typename E>
__device__ __forceinline__ void gemmNS(LA la, const __bf16* __restrict__ Wt,
    const float* __restrict__ bias, int wv, int lane, E epi)
{
  const int ar = lane&15, quad = lane>>4;
  #pragma unroll
  for (int ln=0; ln<NTPW; ln++){
    const int wt = wv*NTPW + ln;
    const __bf16* wp = Wt + (size_t)(wt*16+ar)*(KT*32) + quad*8;
    v8bf wf[KT];
    #pragma unroll
    for (int kt=0;kt<KT;kt++) wf[kt] = *(const v8bf*)(wp + kt*32);
    float4 b4 = *(const float4*)(bias + wt*16 + quad*4);
    #pragma unroll
    for (int mt=0; mt<MT; mt++){
      v4f c; c[0]=b4.x; c[1]=b4.y; c[2]=b4.z; c[3]=b4.w;
      #pragma unroll
      for (int kt=0;kt<KT;kt++)
        c = __builtin_amdgcn_mfma_f32_16x16x32_bf16(wf[kt], la(mt,kt,ar,quad), c, 0,0,0);
      epi(wt*16 + quad*4, mt, ar, c);
    }
  }
}

// LDS map (bytes), total 53120 <= 53248 (proven 3 blocks/CU):
//  Ab   @0      bf16[64][136] 17408  (early: Df f32[12][32])
//  Bb   @17408  bf16[64][136] 17408  (early: TOKIN f32[60][12])
//  Tk   @34816  bf16[64][72]   9216  (early: OBSf f32[12][120]; late: Po bf16[12][64])
//  Pe   @44032  bf16[16][64]   2048
//  Eg   @46080  bf16[16][40]   1280
//  Ru   @47360  bf16[12][30]    736
//  mfb  @48096  bf16[64]        128
//  msfb @48224  bf16[64]        128
//  many @48352  f32[16]          64
//  lga  @48416  f32[64]         256
//  ECX  @48672  bf16[16][64]   2048  (late: pattn f32[12][20])
//  ATTb @50720  bf16[12][100]  2400  (late: Cc bf16[16][64])
__global__ __launch_bounds__(256,3)
void swarm_mfma(P a, const __bf16* __restrict__ ws, int ntok)
{
  __shared__ char smem[53120] __attribute__((aligned(16)));
  __bf16* Ab   = (__bf16*)(smem);
  __bf16* Bb   = (__bf16*)(smem+17408);
  float*  TOKIN= (float*) (smem+17408);
  __bf16* Tk   = (__bf16*)(smem+34816);
  float*  OBSf = (float*) (smem+34816);
  __bf16* Po   = (__bf16*)(smem+34816);
  __bf16* Pe   = (__bf16*)(smem+44032);
  __bf16* Eg   = (__bf16*)(smem+46080);
  __bf16* Ru   = (__bf16*)(smem+47360);
  __bf16* mfb  = (__bf16*)(smem+48096);
  __bf16* msfb = (__bf16*)(smem+48224);
  float*  many = (float*) (smem+48352);
  float*  lga  = (float*) (smem+48416);
  __bf16* ECX  = (__bf16*)(smem+48672);
  float*  pattn= (float*) (smem+48672);
  __bf16* ATTb = (__bf16*)(smem+50720);
  __bf16* Cc   = (__bf16*)(smem+50720);

  const int lane = threadIdx.x & 63;
  const int wv   = threadIdx.x >> 6;
  const int ar   = lane & 15, quad = lane >> 4;
  const long blkT0 = (long)blockIdx.x*12;

  // ================= setup (wave-local tokens 3wv..3wv+2) =================
  for (int it=lane; it<3*117; it+=64){
    int tg=it/117, c=it-tg*117;
    long gt = blkT0 + 3*wv + tg; if (gt>ntok-1) gt=ntok-1;
    OBSf[(3*wv+tg)*120+c] = a.obs[gt*DOBS+c];
  }
  float* Df = (float*)Ab;
  for (int it=lane; it<75; it+=64){
    int tg=it/25, p=it-tg*25, i=p/5, j=p-i*5;
    const float* ob = OBSf + (3*wv+tg)*120 + 32;
    float d2=0.f;
    #pragma unroll
    for (int d=0;d<3;d++){
      float ri=ob[15*i+d]; ri = isfinite(ri)?ri:0.f;
      float rj=ob[15*j+d]; rj = isfinite(rj)?rj:0.f;
      float df=ri-rj; d2 += df*df;
    }
    Df[(3*wv+tg)*32+p]=sqrtf(d2);
  }
  if (lane<15){
    int T=3*wv+lane/5, s=lane%5;
    const float* b = OBSf + T*120 + 32 + 15*s;
    mfb[15*wv+lane] = (__bf16)((fabsf(b[0])>1e-6f||fabsf(b[1])>1e-6f||fabsf(b[2])>1e-6f)?1.f:0.f);
  }
  if (wv==0 && lane>=60){ mfb[lane]=(__bf16)0.f; msfb[lane]=(__bf16)0.f; }
  if (wv==0 && lane>=12 && lane<16) many[lane]=0.f;
  if (lane<3){
    int T=3*wv+lane;
    float any = (float)mfb[T*5]+(float)mfb[T*5+1]+(float)mfb[T*5+2]+(float)mfb[T*5+3]+(float)mfb[T*5+4];
    float anyf = (any>0.f)?1.f:0.f; many[T]=anyf;
    #pragma unroll
    for (int i=0;i<5;i++) msfb[T*5+i] = (anyf>0.f)? mfb[T*5+i] : (__bf16)((i==0)?1.f:0.f);
  }
  if (lane<15){
    int T=3*wv+lane/5, i=lane%5, R=15*wv+lane;
    float dmin=1e9f,dsum=0.f,cnt=0.f;
    #pragma unroll
    for (int j=0;j<5;j++){
      if (j!=i && (float)mfb[T*5+i]>0.5f && (float)mfb[T*5+j]>0.5f){
        float dd=Df[T*32+i*5+j];
        dmin=fminf(dmin,dd); dsum+=dd; cnt+=1.f;
      }
    }
    TOKIN[R*12+10]=dmin;
    TOKIN[R*12+11]=(cnt>0.f)? dsum/(cnt+1e-9f) : 0.f;
  }
  for (int it=lane; it<150; it+=64){
    int tg=it/50, q=it-tg*50, s=q/10, c=q-s*10;
    int T=3*wv+tg;
    const float* b = OBSf + T*120 + 32 + 15*s;
    float v;
    if (c<4)        v=b[11+c];
    else if (c==4)  v=b[9];
    else if (c==5)  v=b[10];
    else if (c<9)   v=b[6+(c-6)];
    else { float a0=b[6],a1=b[7],a2=b[8]; v=sqrtf(a0*a0+a1*a1+a2*a2); }
    TOKIN[(T*5+s)*12+c]=v;
  }
  for (int it=lane; it<96; it+=64){
    int tg=it>>5, c=it&31;
    Eg[(3*wv+tg)*40+c] = (__bf16)OBSf[(3*wv+tg)*120+c];
  }
  for (int it=lane; it<90; it+=64){
    int tg=it/30, c=it-tg*30;
    Ru[(3*wv+tg)*30+c] = (__bf16)OBSf[(3*wv+tg)*120+32+15*(c/6)+(c%6)];
  }
  for (int it=lane; it<192; it+=64){
    int tg=it>>6, c=it&63;
    float acc = a.pr_b[c];
    #pragma unroll
    for (int k=0;k<10;k++) acc += OBSf[(3*wv+tg)*120+107+k]*a.pr_w[k*64+c];
    Pe[(3*wv+tg)*64+c] = (__bf16)gelu_f(acc);
  }
  __syncthreads();   // S0: OBSf/Df/TOKIN producers done; Tk writes may begin

  // ---- P3: tok embed (fp32 K=12) -> Tk rows 15wv..15wv+14; then ln1 -> Ab ----
  {
    float w0[12];
    #pragma unroll
    for (int k=0;k<12;k++) w0[k] = a.tok_w[k*64+lane];
    float tb = a.tok_b[lane];
    for (int r=0;r<15;r++){
      int R = 15*wv + r;
      const float4* tin = (const float4*)(TOKIN + R*12);
      float4 x0 = tin[0], x1 = tin[1], x2 = tin[2];
      float acc = tb;
      acc=fmaf(x0.x,w0[0],acc); acc=fmaf(x0.y,w0[1],acc);
      acc=fmaf(x0.z,w0[2],acc); acc=fmaf(x0.w,w0[3],acc);
      acc=fmaf(x1.x,w0[4],acc); acc=fmaf(x1.y,w0[5],acc);
      acc=fmaf(x1.z,w0[6],acc); acc=fmaf(x1.w,w0[7],acc);
      acc=fmaf(x2.x,w0[8],acc); acc=fmaf(x2.y,w0[9],acc);
      acc=fmaf(x2.z,w0[10],acc); acc=fmaf(x2.w,w0[11],acc);
      Tk[R*72+lane] = (__bf16)(gelu_f(acc)*(float)mfb[R]);
    }
  }
  if (ar<15){   // ln1, own rows (shuffles stay within same-ar groups)
    int R = 15*wv + ar;
    float x[16]; load16f(Tk + R*72 + quad*16, x);
    float s=0.f;
    #pragma unroll
    for (int i=0;i<16;i++) s += x[i];
    s += __shfl_xor(s,16,64); s += __shfl_xor(s,32,64);
    float m = s*(1.f/64.f), q=0.f;
    #pragma unroll
    for (int i=0;i<16;i++){ float d=x[i]-m; q=fmaf(d,d,q); }
    q += __shfl_xor(q,16,64); q += __shfl_xor(q,32,64);
    float rs = __builtin_amdgcn_rsqf(q*(1.f/64.f)+1e-6f);
    v8bf o0,o1;
    #pragma unroll
    for (int i=0;i<8;i++){
      o0[i]=(__bf16)((x[i]  -m)*rs*a.ln1_s[quad*16+i]  +a.ln1_b[quad*16+i]);
      o1[i]=(__bf16)((x[8+i]-m)*rs*a.ln1_s[quad*16+8+i]+a.ln1_b[quad*16+8+i]);
    }
    *(v8bf*)(Ab+R*136+quad*16)=o0; *(v8bf*)(Ab+R*136+quad*16+8)=o1;
  }
  __syncthreads();   // S1

  auto actAb = [&](int mt,int kt,int r,int q){ return *(const v8bf*)(Ab + (size_t)(mt*16+r)*136 + q*8 + kt*32); };
  auto actBb = [&](int mt,int kt,int r,int q){ return *(const v8bf*)(Bb + (size_t)(mt*16+r)*136 + q*8 + kt*32); };
  auto actTk = [&](int mt,int kt,int r,int q){ return *(const v8bf*)(Tk + (size_t)(mt*16+r)*72  + q*8 + kt*32); };

  // ---- QKV: K -> Bb[:,64:], V -> Ab[:,64:], Q -> Bb[:,0:64] ----
  gemmNS<2,4,1>(actAb, ws+W_A1K, a.a1_kb, wv, lane,
    [&](int wb,int mt,int r,v4f c){ v4bf o;
      #pragma unroll
      for (int k=0;k<4;k++) o[k]=(__bf16)c[k];
      *(v4bf*)&Bb[(mt*16+r)*136+64+wb]=o; });
  gemmNS<2,4,1>(actAb, ws+W_A1V, a.a1_vb, wv, lane,
    [&](int wb,int mt,int r,v4f c){ v4bf o;
      #pragma unroll
      for (int k=0;k<4;k++) o[k]=(__bf16)c[k];
      *(v4bf*)&Ab[(mt*16+r)*136+64+wb]=o; });
  gemmNS<2,4,1>(actAb, ws+W_A1Q, a.a1_qb, wv, lane,
    [&](int wb,int mt,int r,v4f c){ v4bf o;
      #pragma unroll
      for (int k=0;k<4;k++) o[k]=(__bf16)c[k];
      *(v4bf*)&Bb[(mt*16+r)*136+wb]=o; });
  __syncthreads();   // S2

  // ---- attn weights + attn@V (wave-local tokens) ----
  if (lane<60){
    int tg=lane/20, rem=lane-tg*20, h=rem/5, i=rem-h*5;
    int T=3*wv+tg;
    bool mi = (float)msfb[T*5+i]>0.5f;
    float qv[16]; load16f(&Bb[(T*5+i)*136 + h*16], qv);
    float lgv[5], mx=NEG_INF_F;
    #pragma unroll
    for (int j=0;j<5;j++){
      float kk[16]; load16f(&Bb[(T*5+j)*136 + 64 + h*16], kk);
      float d=0.f;
      #pragma unroll
      for (int dd=0;dd<16;dd++) d += qv[dd]*kk[dd];
      bool mj = (float)msfb[T*5+j]>0.5f;
      lgv[j] = (mi&&mj)? d*0.25f : NEG_INF_F;
      mx = fmaxf(mx,lgv[j]);
    }
    float sum=0.f, ex[5];
    #pragma unroll
    for (int j=0;j<5;j++){ ex[j]=__expf(lgv[j]-mx); sum+=ex[j]; }
    float inv=1.0f/sum;
    #pragma unroll
    for (int j=0;j<5;j++) ATTb[T*100+(h*5+i)*5+j]=(__bf16)(ex[j]*inv);
  }
  {
    int h = lane>>4;
    #pragma unroll
    for (int tg=0; tg<3; tg++){
      int T=3*wv+tg;
      float v5[5];
      #pragma unroll
      for (int j=0;j<5;j++) v5[j] = (float)Ab[(T*5+j)*136+64+lane];
      #pragma unroll
      for (int i=0;i<5;i++){
        float o=0.f;
        #pragma unroll
        for (int j=0;j<5;j++) o += (float)ATTb[T*100+(h*5+i)*5+j]*v5[j];
        Ab[(T*5+i)*136+lane]=(__bf16)o;
      }
    }
  }
  __syncthreads();   // S3

  // ---- o-proj + residual -> Tk (col-slices) ----
  gemmNS<2,4,1>(actAb, ws+W_A1O, a.a1_ob, wv, lane,
    [&](int wb,int mt,int r,v4f c){
      int R=mt*16+r; float mm=(float)mfb[R];
      v4bf old=*(const v4bf*)&Tk[R*72+wb]; v4bf o;
      #pragma unroll
      for (int k=0;k<4;k++) o[k]=(__bf16)((float)old[k]+c[k]*mm);
      *(v4bf*)&Tk[R*72+wb]=o; });
  __syncthreads();   // S4

  // ---- ln2 -> Ab[:,0:64] (own rows) ----
  if (ar<15){
    int R = 15*wv + ar;
    float x[16]; load16f(Tk + R*72 + quad*16, x);
    float s=0.f;
    #pragma unroll
    for (int i=0;i<16;i++) s += x[i];
    s += __shfl_xor(s,16,64); s += __shfl_xor(s,32,64);
    float m = s*(1.f/64.f), q=0.f;
    #pragma unroll
    for (int i=0;i<16;i++){ float d=x[i]-m; q=fmaf(d,d,q); }
    q += __shfl_xor(q,16,64); q += __shfl_xor(q,32,64);
    float rs = __builtin_amdgcn_rsqf(q*(1.f/64.f)+1e-6f);
    v8bf o0,o1;
    #pragma unroll
    for (int i=0;i<8;i++){
      o0[i]=(__bf16)((x[i]  -m)*rs*a.ln2_s[quad*16+i]  +a.ln2_b[quad*16+i]);
      o1[i]=(__bf16)((x[8+i]-m)*rs*a.ln2_s[quad*16+8+i]+a.ln2_b[quad*16+8+i]);
    }
    *(v8bf*)(Ab+R*136+quad*16)=o0; *(v8bf*)(Ab+R*136+quad*16+8)=o1;
  }
  __syncthreads();   // S5

  // ---- m1 -> Bb[:,0:128] ----
  gemmNS<2,4,2>(actAb, ws+W_M1, a.m1_b, wv, lane,
    [&](int wb,int mt,int r,v4f c){ v4bf o;
      #pragma unroll
      for (int k=0;k<4;k++) o[k]=(__bf16)gelu_f(c[k]);
      *(v4bf*)&Bb[(mt*16+r)*136+wb]=o; });
  __syncthreads();   // S6
  // ---- m2 -> Ab[:,0:128] ----
  gemmNS<4,4,2>(actBb, ws+W_M2, a.m2_b, wv, lane,
    [&](int wb,int mt,int r,v4f c){ v4bf o;
      #pragma unroll
      for (int k=0;k<4;k++) o[k]=(__bf16)gelu_f(c[k]);
      *(v4bf*)&Ab[(mt*16+r)*136+wb]=o; });
  __syncthreads();   // S7
  // ---- m3 -> Tk (resid*mask) ; e1 (token-level) -> Bb rows 0..15 ----
  gemmNS<4,4,1>(actAb, ws+W_M3, a.m3_b, wv, lane,
    [&](int wb,int mt,int r,v4f c){
      int R=mt*16+r; float mm=(float)mfb[R];
      v4bf old=*(const v4bf*)&Tk[R*72+wb]; v4bf o;
      #pragma unroll
      for (int k=0;k<4;k++) o[k]=(__bf16)(((float)old[k]+c[k]*mm)*mm);
      *(v4bf*)&Tk[R*72+wb]=o; });
  gemmNS<1,1,2>([&](int,int,int r,int q){ return *(const v8bf*)(Eg + (size_t)r*40 + q*8); },
    ws+W_E1, a.e1_b, wv, lane,
    [&](int wb,int mt,int r,v4f c){ v4bf o;
      #pragma unroll
      for (int k=0;k<4;k++) o[k]=(__bf16)gelu_f(c[k]);
      *(v4bf*)&Bb[r*136+wb]=o; });
  __syncthreads();   // S8
  // ---- e2 -> Ab rows 0..15 ----
  gemmNS<4,1,2>(actBb, ws+W_E2, a.e2_b, wv, lane,
    [&](int wb,int mt,int r,v4f c){ v4bf o;
      #pragma unroll
      for (int k=0;k<4;k++) o[k]=(__bf16)gelu_f(c[k]);
      *(v4bf*)&Ab[r*136+wb]=o; });
  __syncthreads();   // S9
  // ---- e3 -> ECX rows 0..15 ----
  gemmNS<4,1,1>(actAb, ws+W_E3, a.e3_b, wv, lane,
    [&](int wb,int mt,int r,v4f c){ v4bf o;
      #pragma unroll
      for (int k=0;k<4;k++) o[k]=(__bf16)c[k];
      *(v4bf*)&ECX[r*64+wb]=o; });
  __syncthreads();   // S10
  // ---- l1 (act = [Tk | ECX(token)]) -> Bb[:,0:128] ----
  gemmNS<4,4,2>([&](int mt,int kt,int r,int q){
      int R=mt*16+r;
      return (kt<2) ? *(const v8bf*)(Tk + (size_t)R*72 + q*8 + kt*32)
                    : *(const v8bf*)(ECX + (size_t)((R*205)>>10)*64 + q*8 + (kt-2)*32); },
    ws+W_L1, a.l1_b, wv, lane,
    [&](int wb,int mt,int r,v4f c){ v4bf o;
      #pragma unroll
      for (int k=0;k<4;k++) o[k]=(__bf16)gelu_f(c[k]);
      *(v4bf*)&Bb[(mt*16+r)*136+wb]=o; });
  __syncthreads();   // S11
  // ---- l2 -> Ab[:,0:128] ----
  gemmNS<4,4,2>(actBb, ws+W_L2, a.l2_b, wv, lane,
    [&](int wb,int mt,int r,v4f c){ v4bf o;
      #pragma unroll
      for (int k=0;k<4;k++) o[k]=(__bf16)gelu_f(c[k]);
      *(v4bf*)&Ab[(mt*16+r)*136+wb]=o; });
  __syncthreads();   // S12

  // ---- l3 (own rows) + alpha + v_r/v_u ; kp/vp -> Bb ----
  if (ar<15){
    int R = 15*wv + ar;
    float x[16], y[16];
    load16f(&Ab[R*136 + quad*32], x);
    load16f(&Ab[R*136 + quad*32 + 16], y);
    const float* w = a.l3_w + quad*32;
    float p = 0.f;
    #pragma unroll
    for (int i=0;i<16;i++) p = fmaf(x[i], w[i], p);
    #pragma unroll
    for (int i=0;i<16;i++) p = fmaf(y[i], w[16+i], p);
    p += __shfl_xor(p,16,64); p += __shfl_xor(p,32,64);
    if (quad==0) lga[R] = p + a.l3_b[0];
  }
  gemmNS<2,4,1>(actTk, ws+W_PK, a.p_kb, wv, lane,
    [&](int wb,int mt,int r,v4f c){ v4bf o;
      #pragma unroll
      for (int k=0;k<4;k++) o[k]=(__bf16)c[k];
      *(v4bf*)&Bb[(mt*16+r)*136+wb]=o; });
  gemmNS<2,4,1>(actTk, ws+W_PV, a.p_vb, wv, lane,
    [&](int wb,int mt,int r,v4f c){ v4bf o;
      #pragma unroll
      for (int k=0;k<4;k++) o[k]=(__bf16)c[k];
      *(v4bf*)&Bb[(mt*16+r)*136+64+wb]=o; });
  if (lane<3){
    int T=3*wv+lane;
    float ml[5], mx=-1e9f;
    #pragma unroll
    for (int i=0;i<5;i++){ ml[i]=((float)mfb[T*5+i]>0.5f)? lga[T*5+i] : -1e9f; mx=fmaxf(mx,ml[i]); }
    float den=0.f, e[5];
    #pragma unroll
    for (int i=0;i<5;i++){ e[i]=__expf(ml[i]-mx)*(float)mfb[T*5+i]; den+=e[i]; }
    float inv=1.0f/(den+1e-9f);
    #pragma unroll
    for (int i=0;i<5;i++) lga[T*5+i]=e[i]*inv;
  }
  if (lane<18){
    int tg=lane/6, c=lane-tg*6;
    int T=3*wv+tg;
    float v=0.f;
    #pragma unroll
    for (int i=0;i<5;i++) v += lga[T*5+i]*(float)Ru[T*30+i*6+c];
    long tk = blkT0 + T;
    if (tk<ntok) a.out[tk*134+128+c]=v;
  }
  __syncthreads();   // S13

  // ---- pooling attn + pooled-o (wave-local tokens) ----
  if (lane<12){
    const float* qg = (const float*)(ws + W_QP);
    int tg=lane>>2, h=lane&3;
    int T=3*wv+tg;
    float qv[16];
    #pragma unroll
    for (int dd=0;dd<16;dd++) qv[dd]=qg[h*16+dd];
    float lgv[5], mx=NEG_INF_F;
    #pragma unroll
    for (int j=0;j<5;j++){
      float kk[16]; load16f(&Bb[(T*5+j)*136 + h*16], kk);
      float d=0.f;
      #pragma unroll
      for (int dd=0;dd<16;dd++) d += qv[dd]*kk[dd];
      lgv[j] = ((float)msfb[T*5+j]>0.5f)? d*0.25f : NEG_INF_F;
      mx = fmaxf(mx,lgv[j]);
    }
    float sum=0.f, ex[5];
    #pragma unroll
    for (int j=0;j<5;j++){ ex[j]=__expf(lgv[j]-mx); sum+=ex[j]; }
    float inv=1.0f/sum;
    #pragma unroll
    for (int j=0;j<5;j++) pattn[T*20+h*5+j]=ex[j]*inv;
  }
  for (int it=lane; it<192; it+=64){
    int tg=it>>6, c=it&63, h=c>>4;
    int T=3*wv+tg;
    float o=0.f;
    #pragma unroll
    for (int j=0;j<5;j++)
      o += pattn[T*20+h*5+j]*(float)Bb[(T*5+j)*136+64+c];
    Po[T*64+c]=(__bf16)o;
  }
  __syncthreads();   // S14

  // ---- p_ow -> Cc (x many) ----
  gemmNS<2,1,1>([&](int,int kt,int r,int q){ return *(const v8bf*)(Po + (size_t)r*64 + q*8 + kt*32); },
    ws+W_PO, a.p_ob, wv, lane,
    [&](int wb,int mt,int r,v4f c){
      float mm = many[r];
      v4bf o;
      #pragma unroll
      for (int k=0;k<4;k++) o[k]=(__bf16)(c[k]*mm);
      *(v4bf*)&Cc[r*64+wb]=o; });
  __syncthreads();   // S15

  // ---- h1 (act = [Eg | Cc | Pe], K=160) -> Bb rows 0..15 ----
  gemmNS<5,1,2>([&](int,int kt,int r,int q){
      if (kt==0) return *(const v8bf*)(Eg + (size_t)r*40 + q*8);
      if (kt<3)  return *(const v8bf*)(Cc + (size_t)r*64 + q*8 + (kt-1)*32);
      return *(const v8bf*)(Pe + (size_t)r*64 + q*8 + (kt-3)*32); },
    ws+W_H1, a.h1_b, wv, lane,
    [&](int wb,int mt,int r,v4f c){ v4bf o;
      #pragma unroll
      for (int k=0;k<4;k++) o[k]=(__bf16)gelu_f(c[k]);
      *(v4bf*)&Bb[r*136+wb]=o; });
  __syncthreads();   // S16
  // ---- h2 -> Ab rows 0..15 ----
  gemmNS<4,1,2>(actBb, ws+W_H2, a.h2_b, wv, lane,
    [&](int wb,int mt,int r,v4f c){ v4bf o;
      #pragma unroll
      for (int k=0;k<4;k++) o[k]=(__bf16)gelu_f(c[k]);
      *(v4bf*)&Ab[r*136+wb]=o; });
  __syncthreads();   // S17
  // ---- h3 -> out ----
  gemmNS<4,1,2>(actAb, ws+W_H3, a.h3_b, wv, lane,
    [&](int wb,int mt,int r,v4f c){
      long tk = blkT0 + r;
      if (r<12 && tk<ntok){
        float2* o2 = (float2*)&a.out[tk*134 + wb];
        o2[0] = make_float2(c[0], c[1]);
        o2[1] = make_float2(c[2], c[3]);
      } });
}

extern "C" void kernel_launch(void* const* d_in, const int* in_sizes, int n_in,
                              void* d_out, int out_size, void* d_ws, size_t ws_size,
                              hipStream_t stream)
{
  P a;
  const float** pp = reinterpret_cast<const float**>(&a);
  for (int i=0;i<50;i++) pp[i] = reinterpret_cast<const float*>(d_in[i]);
  a.out = reinterpret_cast<float*>(d_out);
  int ntok = in_sizes[0] / DOBS;   // 65536

  __bf16* ws = reinterpret_cast<__bf16*>(d_ws);
  hipLaunchKernelGGL(prep_w, dim3(173), dim3(256), 0, stream, a, ws);
  hipLaunchKernelGGL(swarm_mfma, dim3((ntok+11)/12), dim3(256), 0, stream, a, ws, ntok);
}